// Round 5
// baseline (232.524 us; speedup 1.0000x reference)
//
#include <hip/hip_runtime.h>

#define H 4
#define Nq 4096
#define SEG 8
#define NKT ((Nq / SEG) / 64)
#define LOG2E 1.44269504088896340736f

typedef unsigned short ushortT;
typedef __attribute__((ext_vector_type(4))) short short4T;
typedef __attribute__((ext_vector_type(8))) short short8;
typedef __attribute__((ext_vector_type(4))) float floatx4;

// round-half-up f32 -> bf16 (inputs finite)
static __device__ __forceinline__ ushortT f2bf(float x) {
    unsigned int u = __builtin_bit_cast(unsigned int, x);
    return (ushortT)((u + 0x8000u) >> 16);
}

// ---------------------------------------------------------------------------
// Kernel 1: QKV projection + stack + vec-activation; z==6 does pos features.
//   pq4 = (2c*x,2c*y,2c*z,-c|p|^2), pk4 = (x,y,z,-c|p|^2), c = log2e/r0sq[h].
// ---------------------------------------------------------------------------
__global__ __launch_bounds__(256) void qkv_kernel(
    const float* __restrict__ ax, const float* __restrict__ vx,
    const float* __restrict__ pos_q, const float* __restrict__ pos_k,
    const float* __restrict__ Waq, const float* __restrict__ Wvq,
    const float* __restrict__ Wak, const float* __restrict__ Wvk,
    const float* __restrict__ Wav, const float* __restrict__ Wvv,
    ushortT* __restrict__ Qg, ushortT* __restrict__ Kg, ushortT* __restrict__ Vtg,
    floatx4* __restrict__ pq4, floatx4* __restrict__ pk4)
{
    const int h = blockIdx.y;
    const int n = blockIdx.x * 256 + threadIdx.x;

    if (blockIdx.z == 6) {      // pos feature branch (block-uniform)
        const float c = LOG2E / (float)(1 << (2 * h));
        {
            const float* p = pos_q + ((size_t)h * Nq + n) * 3;
            const float x = p[0], y = p[1], z = p[2];
            pq4[(size_t)h * Nq + n] = (floatx4){2.f*c*x, 2.f*c*y, 2.f*c*z,
                                                -c * (x*x + y*y + z*z)};
        }
        {
            const float* p = pos_k + ((size_t)h * Nq + n) * 3;
            const float x = p[0], y = p[1], z = p[2];
            pk4[(size_t)h * Nq + n] = (floatx4){x, y, z, -c * (x*x + y*y + z*z)};
        }
        return;
    }

    const int mat   = blockIdx.z >> 1;
    const int chalf = blockIdx.z & 1;
    const int c0    = chalf * 8;

    const float* Wa = (mat == 0 ? Waq : (mat == 1 ? Wak : Wav)) + h * (16 * 64);
    const float* Wv = (mat == 0 ? Wvq : (mat == 1 ? Wvk : Wvv)) + h * (16 * 16);

    float axr[64];
    {
        const floatx4* p = (const floatx4*)(ax + (size_t)n * 64);
        #pragma unroll
        for (int i = 0; i < 16; i++) {
            floatx4 t = p[i];
            axr[4*i+0] = t.x; axr[4*i+1] = t.y; axr[4*i+2] = t.z; axr[4*i+3] = t.w;
        }
    }
    float vxr[48];
    {
        const floatx4* p = (const floatx4*)(vx + (size_t)n * 48);
        #pragma unroll
        for (int i = 0; i < 12; i++) {
            floatx4 t = p[i];
            vxr[4*i+0] = t.x; vxr[4*i+1] = t.y; vxr[4*i+2] = t.z; vxr[4*i+3] = t.w;
        }
    }

    float acca[8] = {};
    float accv[8][3] = {};
    #pragma unroll
    for (int d = 0; d < 64; d++) {
        #pragma unroll
        for (int cc = 0; cc < 8; cc++)
            acca[cc] = fmaf(Wa[(c0 + cc) * 64 + d], axr[d], acca[cc]);
    }
    #pragma unroll
    for (int j = 0; j < 16; j++) {
        #pragma unroll
        for (int cc = 0; cc < 8; cc++) {
            const float w = Wv[(c0 + cc) * 16 + j];
            accv[cc][0] = fmaf(w, vxr[3*j+0], accv[cc][0]);
            accv[cc][1] = fmaf(w, vxr[3*j+1], accv[cc][1]);
            accv[cc][2] = fmaf(w, vxr[3*j+2], accv[cc][2]);
        }
    }

    const float sc_extra = (mat == 0) ? LOG2E : 1.0f;
    __attribute__((aligned(16))) ushortT ob[32];
    #pragma unroll
    for (int cc = 0; cc < 8; cc++) {
        float a = acca[cc], v0 = accv[cc][0], v1 = accv[cc][1], v2 = accv[cc][2];
        float s = 1.0f;
        if (mat < 2) {
            const float nsq = a*a + v0*v0 + v1*v1 + v2*v2;
            s = rsqrtf(sqrtf(1.0f + nsq)) * sc_extra;   // (1+nsq)^(-1/4)
        }
        ob[4*cc+0] = f2bf(a  * s);
        ob[4*cc+1] = f2bf(v0 * s);
        ob[4*cc+2] = f2bf(v1 * s);
        ob[4*cc+3] = f2bf(v2 * s);
    }

    if (mat < 2) {
        ushortT* dst = (mat == 0 ? Qg : Kg) + ((size_t)(h * Nq + n)) * 64 + c0 * 4;
        #pragma unroll
        for (int i = 0; i < 4; i++) ((short8*)dst)[i] = ((const short8*)ob)[i];
    } else {
        #pragma unroll
        for (int cc = 0; cc < 8; cc++)
            #pragma unroll
            for (int j = 0; j < 4; j++) {
                const int d = c0 * 4 + cc * 4 + j;
                Vtg[((size_t)(h * 64 + d)) * Nq + n] = ob[4*cc+j];  // coalesced
            }
    }
}

// ---------------------------------------------------------------------------
// Kernel 2 (v5): ZERO-LDS flash attention. One wave per block (32 queries).
//   No barriers, no DMA, no LDS: K fragments read directly from global
//   (b128, 16 full lines/instr, L2-resident 64 KB/seg), V from Vt[feat][N]
//   (b64 pairs, 16 half-lines/instr), pos via 4-way-broadcast b128.
//   S computed transposed via mfma(K,Q) -> P stays in registers; PV K=32.
//   Row-sums l via extra MFMA against a ones-B operand.
// ---------------------------------------------------------------------------
__global__ __launch_bounds__(64, 4) void attn_kernel(
    const ushortT* __restrict__ Qg, const ushortT* __restrict__ Kg,
    const ushortT* __restrict__ Vtg,
    const floatx4* __restrict__ pq4, const floatx4* __restrict__ pk4,
    float* __restrict__ partO, float* __restrict__ partL)
{
    const int lane = threadIdx.x & 63;
    const int quad = lane >> 4;
    const int ln   = lane & 15;
    const int h    = blockIdx.y;
    const int seg  = blockIdx.z;
    const int qw   = blockIdx.x * 32;     // this wave's 32 queries

    // Q fragments (B-operand; Q pre-scaled by log2e) + pq features
    short8 qf[2][2];
    floatx4 pql[2];
    #pragma unroll
    for (int qg = 0; qg < 2; qg++) {
        const short8* qp = (const short8*)(Qg + ((size_t)(h*Nq + qw + qg*16 + ln))*64 + quad*8);
        qf[qg][0] = qp[0];
        qf[qg][1] = qp[4];
        pql[qg]   = pq4[(size_t)h*Nq + qw + qg*16 + ln];
    }

    const ushortT* Kh  = Kg  + (size_t)h * Nq * 64;
    const ushortT* Vh  = Vtg + (size_t)h * 64 * Nq;
    const floatx4* ph4 = pk4 + (size_t)h * Nq;

    floatx4 O[2][4] = {};          // [qg][featgroup]: q=quad*4+r, feat=g*16+ln
    floatx4 Ol[2]   = {};          // row-sums l via ones-MFMA
    const short8 vones = {(short)0x3F80, (short)0x3F80, (short)0x3F80, (short)0x3F80,
                          (short)0x3F80, (short)0x3F80, (short)0x3F80, (short)0x3F80};

    #pragma unroll 1
    for (int kt = 0; kt < NKT; kt++) {
        const int k0 = (seg * NKT + kt) * 64;

        #pragma unroll
        for (int c2 = 0; c2 < 2; c2++) {
            short4T ph[2][2];      // [kk2][qg] P bf16, keys quad*4+r
            #pragma unroll
            for (int kk2 = 0; kk2 < 2; kk2++) {
                const int kk  = c2*2 + kk2;
                const int row = k0 + kk*16 + ln;
                const short8 kf0 = *(const short8*)(Kh + (size_t)row*64 + quad*8);
                const short8 kf1 = *(const short8*)(Kh + (size_t)row*64 + 32 + quad*8);
                const floatx4 pk0 = ph4[k0 + kk*16 + quad*4 + 0];
                const floatx4 pk1 = ph4[k0 + kk*16 + quad*4 + 1];
                const floatx4 pk2 = ph4[k0 + kk*16 + quad*4 + 2];
                const floatx4 pk3 = ph4[k0 + kk*16 + quad*4 + 3];
                #pragma unroll
                for (int qg = 0; qg < 2; qg++) {
                    floatx4 S = {0.f, 0.f, 0.f, 0.f};
                    S = __builtin_amdgcn_mfma_f32_16x16x32_bf16(kf0, qf[qg][0], S, 0, 0, 0);
                    S = __builtin_amdgcn_mfma_f32_16x16x32_bf16(kf1, qf[qg][1], S, 0, 0, 0);
                    const floatx4 pq = pql[qg];
                    const float p0v = __builtin_amdgcn_exp2f(S[0] +
                        fmaf(pq.x, pk0.x, fmaf(pq.y, pk0.y, fmaf(pq.z, pk0.z, pq.w + pk0.w))));
                    const float p1v = __builtin_amdgcn_exp2f(S[1] +
                        fmaf(pq.x, pk1.x, fmaf(pq.y, pk1.y, fmaf(pq.z, pk1.z, pq.w + pk1.w))));
                    const float p2v = __builtin_amdgcn_exp2f(S[2] +
                        fmaf(pq.x, pk2.x, fmaf(pq.y, pk2.y, fmaf(pq.z, pk2.z, pq.w + pk2.w))));
                    const float p3v = __builtin_amdgcn_exp2f(S[3] +
                        fmaf(pq.x, pk3.x, fmaf(pq.y, pk3.y, fmaf(pq.z, pk3.z, pq.w + pk3.w))));
                    ph[kk2][qg] = (short4T){ (short)f2bf(p0v), (short)f2bf(p1v),
                                             (short)f2bf(p2v), (short)f2bf(p3v) };
                }
            }
            // P A-frags for K=32: position quad*8+j <-> key c2*32 + (j<4 ? quad*4+j
            //                                                     : 16+quad*4+(j-4))
            short8 pf[2];
            #pragma unroll
            for (int qg = 0; qg < 2; qg++)
                pf[qg] = (short8){ ph[0][qg].x, ph[0][qg].y, ph[0][qg].z, ph[0][qg].w,
                                   ph[1][qg].x, ph[1][qg].y, ph[1][qg].z, ph[1][qg].w };
            #pragma unroll
            for (int g = 0; g < 4; g++) {
                const ushortT* vb = Vh + (size_t)(g*16 + ln)*Nq + k0 + c2*32 + quad*4;
                const short4T vlo = *(const short4T*)(vb);
                const short4T vhi = *(const short4T*)(vb + 16);
                const short8 vf = (short8){ vlo.x, vlo.y, vlo.z, vlo.w,
                                            vhi.x, vhi.y, vhi.z, vhi.w };
                O[0][g] = __builtin_amdgcn_mfma_f32_16x16x32_bf16(pf[0], vf, O[0][g], 0, 0, 0);
                O[1][g] = __builtin_amdgcn_mfma_f32_16x16x32_bf16(pf[1], vf, O[1][g], 0, 0, 0);
            }
            Ol[0] = __builtin_amdgcn_mfma_f32_16x16x32_bf16(pf[0], vones, Ol[0], 0, 0, 0);
            Ol[1] = __builtin_amdgcn_mfma_f32_16x16x32_bf16(pf[1], vones, Ol[1], 0, 0, 0);
        }
    }

    const int hs = h * SEG + seg;
    #pragma unroll
    for (int qg = 0; qg < 2; qg++)
        #pragma unroll
        for (int r = 0; r < 4; r++) {
            const int q = qw + qg*16 + quad*4 + r;
            const size_t base = ((size_t)hs * Nq + q) * 64;
            #pragma unroll
            for (int g = 0; g < 4; g++)
                partO[base + g*16 + ln] = O[qg][g][r];
        }
    if (ln == 0) {
        #pragma unroll
        for (int qg = 0; qg < 2; qg++)
            #pragma unroll
            for (int r = 0; r < 4; r++)
                partL[(size_t)hs * Nq + qw + qg*16 + quad*4 + r] = Ol[qg][r];
    }
}

// ---------------------------------------------------------------------------
// Kernel 3 (fused): merge split-K partials + normalize + project.
//   Per block: 64 queries. ay = O[0:16]; vy[i][v] = O[16+3i+v].
// ---------------------------------------------------------------------------
__global__ __launch_bounds__(256) void finish_kernel(
    const float* __restrict__ partO, const float* __restrict__ partL,
    const float* __restrict__ Wao, const float* __restrict__ Wvo,
    float* __restrict__ out)
{
    __shared__ float T[64 * 65];
    __shared__ float linvS[4][64];
    const int tid  = threadIdx.x;
    const int w    = tid >> 6;
    const int lane = tid & 63;
    const int q0   = blockIdx.x * 64;
    const int n    = q0 + lane;

    // all-head 1/(l*sqrt(N)): thread (w=h, lane=q)
    {
        float s = 0.f;
        #pragma unroll
        for (int sg = 0; sg < SEG; sg++)
            s += partL[(size_t)(w * SEG + sg) * Nq + q0 + lane];
        linvS[w][lane] = 1.0f / (s * 64.0f);
    }
    __syncthreads();

    float aacc[16] = {};
    float vacc[4][3] = {};

    for (int h = 0; h < 4; h++) {
        #pragma unroll
        for (int k = 0; k < 16; k++) {
            const int q = k * 4 + w;
            const int d = lane;
            float acc = 0.f;
            #pragma unroll
            for (int sg = 0; sg < SEG; sg++)
                acc += partO[((size_t)(h * SEG + sg) * Nq + q0 + q) * 64 + d];
            T[d * 65 + q] = acc * linvS[h][q];
        }
        __syncthreads();

        float oh[64];
        #pragma unroll
        for (int d = 0; d < 64; d++)
            oh[d] = T[d * 65 + lane];
        #pragma unroll
        for (int jj = 0; jj < 16; jj++) {
            const int j = w * 16 + jj;
            float acc = aacc[jj];
            #pragma unroll
            for (int i = 0; i < 16; i++)
                acc = fmaf(Wao[(h * 64 + j) * 16 + i], oh[i], acc);
            aacc[jj] = acc;
        }
        #pragma unroll
        for (int jj = 0; jj < 4; jj++) {
            const int j = w * 4 + jj;
            #pragma unroll
            for (int i = 0; i < 16; i++) {
                const float wv = Wvo[(h * 16 + j) * 16 + i];
                vacc[jj][0] = fmaf(wv, oh[16 + 3 * i + 0], vacc[jj][0]);
                vacc[jj][1] = fmaf(wv, oh[16 + 3 * i + 1], vacc[jj][1]);
                vacc[jj][2] = fmaf(wv, oh[16 + 3 * i + 2], vacc[jj][2]);
            }
        }
        __syncthreads();   // T reused next h
    }

    #pragma unroll
    for (int jj = 0; jj < 16; jj++)
        out[(size_t)n * 64 + w * 16 + jj] = aacc[jj];
    float* outv = out + (size_t)Nq * 64;
    #pragma unroll
    for (int jj = 0; jj < 4; jj++)
        #pragma unroll
        for (int v = 0; v < 3; v++)
            outv[((size_t)n * 16 + w * 4 + jj) * 3 + v] = vacc[jj][v];
}

// ---------------------------------------------------------------------------
extern "C" void kernel_launch(void* const* d_in, const int* in_sizes, int n_in,
                              void* d_out, int out_size, void* d_ws, size_t ws_size,
                              hipStream_t stream)
{
    const float* ax    = (const float*)d_in[0];
    const float* vx    = (const float*)d_in[1];
    const float* pos_k = (const float*)d_in[2];
    const float* pos_q = (const float*)d_in[3];
    const float* Waq   = (const float*)d_in[4];
    const float* Wvq   = (const float*)d_in[5];
    const float* Wak   = (const float*)d_in[6];
    const float* Wvk   = (const float*)d_in[7];
    const float* Wav   = (const float*)d_in[8];
    const float* Wvv   = (const float*)d_in[9];
    const float* Wao   = (const float*)d_in[10];
    const float* Wvo   = (const float*)d_in[11];
    float* out = (float*)d_out;

    const size_t MB = 1024 * 1024;
    char* ws = (char*)d_ws;
    // layout: Q(2MB) K(2MB) Vt(2MB) pq4(256K) pk4(256K) partO(33.6MB) partL(512K)
    ushortT* Qg   = (ushortT*)(ws);
    ushortT* Kg   = (ushortT*)(ws + 2*MB);
    ushortT* Vtg  = (ushortT*)(ws + 4*MB);
    floatx4* pq4  = (floatx4*)(ws + 6*MB);
    floatx4* pk4  = (floatx4*)(ws + 6*MB + (size_t)H*Nq*16);
    float*  partO = (float*)(ws + 6*MB + (size_t)2*H*Nq*16);
    float*  partL = (float*)((char*)partO + (size_t)H*SEG*Nq*64*4);

    qkv_kernel<<<dim3(Nq/256, H, 7), 256, 0, stream>>>(
        ax, vx, pos_q, pos_k, Waq, Wvq, Wak, Wvk, Wav, Wvv, Qg, Kg, Vtg, pq4, pk4);
    attn_kernel<<<dim3(Nq/32, H, SEG), 64, 0, stream>>>(
        Qg, Kg, Vtg, pq4, pk4, partO, partL);
    finish_kernel<<<dim3(Nq/64), 256, 0, stream>>>(partO, partL, Wao, Wvo, out);
}

// Round 7
// 163.489 us; speedup vs baseline: 1.4223x; 1.4223x over previous
//
#include <hip/hip_runtime.h>

#define H 4
#define Nq 4096
#define SEG 8
#define NKT ((Nq / SEG) / 64)
#define LOG2E 1.44269504088896340736f

typedef unsigned short ushortT;
typedef __attribute__((ext_vector_type(4))) short short4T;
typedef __attribute__((ext_vector_type(8))) short short8;
typedef __attribute__((ext_vector_type(4))) float floatx4;

// raw pipeline primitives (R4-verified): wait own DMA, barrier without the
// compiler's full vmcnt/lgkmcnt drain (which would also wait the prefetch).
#define WAIT_VM0() asm volatile("s_waitcnt vmcnt(0)" ::: "memory")
#define BARRIER()  asm volatile("s_barrier" ::: "memory")

// round-half-up f32 -> bf16 (inputs finite)
static __device__ __forceinline__ ushortT f2bf(float x) {
    unsigned int u = __builtin_bit_cast(unsigned int, x);
    return (ushortT)((u + 0x8000u) >> 16);
}

// DPP quad_perm broadcast: every lane in each 4-lane group gets slot R's value.
template <int R>
static __device__ __forceinline__ float qbcast(float x) {
    return __builtin_bit_cast(float, __builtin_amdgcn_mov_dpp(
        __builtin_bit_cast(int, x), R * 0x55, 0xf, 0xf, true));
}

// async global->LDS: PER-LANE global address -> LDS uniform base + lane*16.
// (R6 bug: passing a uniform global address makes every lane fetch the same
//  16B; the lane offset is implicit only on the LDS side.)
static __device__ __forceinline__ void gld16(const void* g, void* l) {
    __builtin_amdgcn_global_load_lds(
        reinterpret_cast<const __attribute__((address_space(1))) unsigned int*>(
            reinterpret_cast<unsigned long long>(g)),
        reinterpret_cast<__attribute__((address_space(3))) unsigned int*>(
            static_cast<unsigned int>(reinterpret_cast<unsigned long long>(l))),
        16, 0, 0);
}

// ---------------------------------------------------------------------------
// Kernel 1: QKV projection + stack + vec-activation; z==6 does pos features.
//   pq4 = (2c*x,2c*y,2c*z,-c|p|^2), pk4 = (x,y,z,-c|p|^2), c = log2e/r0sq[h].
// ---------------------------------------------------------------------------
__global__ __launch_bounds__(256) void qkv_kernel(
    const float* __restrict__ ax, const float* __restrict__ vx,
    const float* __restrict__ pos_q, const float* __restrict__ pos_k,
    const float* __restrict__ Waq, const float* __restrict__ Wvq,
    const float* __restrict__ Wak, const float* __restrict__ Wvk,
    const float* __restrict__ Wav, const float* __restrict__ Wvv,
    ushortT* __restrict__ Qg, ushortT* __restrict__ Kg, ushortT* __restrict__ Vtg,
    floatx4* __restrict__ pq4, floatx4* __restrict__ pk4)
{
    const int h = blockIdx.y;
    const int n = blockIdx.x * 256 + threadIdx.x;

    if (blockIdx.z == 6) {      // pos feature branch (block-uniform)
        const float c = LOG2E / (float)(1 << (2 * h));
        {
            const float* p = pos_q + ((size_t)h * Nq + n) * 3;
            const float x = p[0], y = p[1], z = p[2];
            pq4[(size_t)h * Nq + n] = (floatx4){2.f*c*x, 2.f*c*y, 2.f*c*z,
                                                -c * (x*x + y*y + z*z)};
        }
        {
            const float* p = pos_k + ((size_t)h * Nq + n) * 3;
            const float x = p[0], y = p[1], z = p[2];
            pk4[(size_t)h * Nq + n] = (floatx4){x, y, z, -c * (x*x + y*y + z*z)};
        }
        return;
    }

    const int mat   = blockIdx.z >> 1;
    const int chalf = blockIdx.z & 1;
    const int c0    = chalf * 8;

    const float* Wa = (mat == 0 ? Waq : (mat == 1 ? Wak : Wav)) + h * (16 * 64);
    const float* Wv = (mat == 0 ? Wvq : (mat == 1 ? Wvk : Wvv)) + h * (16 * 16);

    float axr[64];
    {
        const floatx4* p = (const floatx4*)(ax + (size_t)n * 64);
        #pragma unroll
        for (int i = 0; i < 16; i++) {
            floatx4 t = p[i];
            axr[4*i+0] = t.x; axr[4*i+1] = t.y; axr[4*i+2] = t.z; axr[4*i+3] = t.w;
        }
    }
    float vxr[48];
    {
        const floatx4* p = (const floatx4*)(vx + (size_t)n * 48);
        #pragma unroll
        for (int i = 0; i < 12; i++) {
            floatx4 t = p[i];
            vxr[4*i+0] = t.x; vxr[4*i+1] = t.y; vxr[4*i+2] = t.z; vxr[4*i+3] = t.w;
        }
    }

    float acca[8] = {};
    float accv[8][3] = {};
    #pragma unroll
    for (int d = 0; d < 64; d++) {
        #pragma unroll
        for (int cc = 0; cc < 8; cc++)
            acca[cc] = fmaf(Wa[(c0 + cc) * 64 + d], axr[d], acca[cc]);
    }
    #pragma unroll
    for (int j = 0; j < 16; j++) {
        #pragma unroll
        for (int cc = 0; cc < 8; cc++) {
            const float w = Wv[(c0 + cc) * 16 + j];
            accv[cc][0] = fmaf(w, vxr[3*j+0], accv[cc][0]);
            accv[cc][1] = fmaf(w, vxr[3*j+1], accv[cc][1]);
            accv[cc][2] = fmaf(w, vxr[3*j+2], accv[cc][2]);
        }
    }

    const float sc_extra = (mat == 0) ? LOG2E : 1.0f;
    __attribute__((aligned(16))) ushortT ob[32];
    #pragma unroll
    for (int cc = 0; cc < 8; cc++) {
        float a = acca[cc], v0 = accv[cc][0], v1 = accv[cc][1], v2 = accv[cc][2];
        float s = 1.0f;
        if (mat < 2) {
            const float nsq = a*a + v0*v0 + v1*v1 + v2*v2;
            s = rsqrtf(sqrtf(1.0f + nsq)) * sc_extra;   // (1+nsq)^(-1/4)
        }
        ob[4*cc+0] = f2bf(a  * s);
        ob[4*cc+1] = f2bf(v0 * s);
        ob[4*cc+2] = f2bf(v1 * s);
        ob[4*cc+3] = f2bf(v2 * s);
    }

    if (mat < 2) {
        ushortT* dst = (mat == 0 ? Qg : Kg) + ((size_t)(h * Nq + n)) * 64 + c0 * 4;
        #pragma unroll
        for (int i = 0; i < 4; i++) ((short8*)dst)[i] = ((const short8*)ob)[i];
    } else {
        #pragma unroll
        for (int cc = 0; cc < 8; cc++)
            #pragma unroll
            for (int j = 0; j < 4; j++) {
                const int d = c0 * 4 + cc * 4 + j;
                Vtg[((size_t)(h * 64 + d)) * Nq + n] = ob[4*cc+j];  // coalesced
            }
    }
}

// ---------------------------------------------------------------------------
// Kernel 2 (v7 = v6 + pos-DMA fix): pipelined transposed-S flash attention,
//   4 waves/block sharing one staged 64-key tile; double-buffered LDS with
//   raw s_barrier/vmcnt pipeline; pos via one b128 read + DPP quad_perm
//   broadcasts; P in registers; l via ones-MFMA.
// ---------------------------------------------------------------------------
__global__ __launch_bounds__(256, 4) void attn_kernel(
    const ushortT* __restrict__ Qg, const ushortT* __restrict__ Kg,
    const ushortT* __restrict__ Vtg,
    const floatx4* __restrict__ pq4, const floatx4* __restrict__ pk4,
    float* __restrict__ partO, float* __restrict__ partL)
{
    __shared__ __attribute__((aligned(16))) ushortT kE[2][64 * 64];  // swizzled [key][feat]
    __shared__ __attribute__((aligned(16))) ushortT vE[2][64 * 64];  // swizzled [feat][key]
    __shared__ __attribute__((aligned(16))) floatx4 posE[2][64];     // pk features

    const int tid  = threadIdx.x;
    const int w    = tid >> 6;
    const int lane = tid & 63;
    const int quad = lane >> 4;
    const int ln   = lane & 15;
    const int m7   = ln & 7;
    const int h    = blockIdx.y;
    const int seg  = blockIdx.z;
    const int qw   = blockIdx.x * 128 + w * 32;     // wave's 32 queries

    // Q fragments (B-operand; Q pre-scaled by log2e) + pq features
    short8 qf[2][2];
    floatx4 pql[2];
    #pragma unroll
    for (int qg = 0; qg < 2; qg++) {
        const short8* qp = (const short8*)(Qg + ((size_t)(h*Nq + qw + qg*16 + ln))*64 + quad*8);
        qf[qg][0] = qp[0];
        qf[qg][1] = qp[4];
        pql[qg]   = pq4[(size_t)h*Nq + qw + qg*16 + ln];
    }

    const ushortT* Khg = Kg  + (size_t)h * Nq * 64;
    const ushortT* Vhg = Vtg + (size_t)h * 64 * Nq;
    const floatx4* ph4 = pk4 + (size_t)h * Nq;

    floatx4 O[2][4] = {};          // [qg][featgroup]: q=quad*4+r, feat=g*16+ln
    floatx4 Ol[2]   = {};          // row-sums l via ones-MFMA
    const short8 vones = {(short)0x3F80, (short)0x3F80, (short)0x3F80, (short)0x3F80,
                          (short)0x3F80, (short)0x3F80, (short)0x3F80, (short)0x3F80};

    // --- DMA stage of one 64-key tile into buffer b (block-cooperative) ---
    auto stage = [&](int k0, int b) {
        #pragma unroll
        for (int i = 0; i < 2; i++) {
            const int cbase = i * 256 + w * 64;     // wave-uniform LDS chunk base
            const int cc    = cbase + lane;         // 0..511
            const int row   = cc >> 3;
            const int part  = (cc & 7) ^ (row & 7); // XOR swizzle
            gld16(Khg + (size_t)(k0 + row)*64 + part*8, (char*)kE[b] + cbase*16);
            gld16(Vhg + (size_t)row*Nq + k0 + part*8, (char*)vE[b] + cbase*16);
        }
        if (w == 3)                                  // wave-uniform branch
            gld16(ph4 + k0 + lane, (char*)posE[b]);  // PER-LANE global addr (fix)
    };

    stage(seg * NKT * 64, 0);
    int buf = 0;

    #pragma unroll 1
    for (int kt = 0; kt < NKT; kt++) {
        WAIT_VM0();       // own DMA(t) complete
        BARRIER();        // all waves' DMA(t) complete; compute(t-1) done
        if (kt + 1 < NKT) stage((seg * NKT + kt + 1) * 64, buf ^ 1);  // overlaps compute(t)

        const ushortT* kb = kE[buf];
        const ushortT* vb = vE[buf];
        const floatx4* pb = posE[buf];

        #pragma unroll
        for (int c2 = 0; c2 < 2; c2++) {
            short4T ph[2][2];      // [kk2][qg] P bf16, keys quad*4+r
            #pragma unroll
            for (int kk2 = 0; kk2 < 2; kk2++) {
                const int kk  = c2*2 + kk2;
                const int row = kk*16 + ln;
                const int p0  = quad ^ m7;
                const short8 kf0 = *(const short8*)&kb[row*64 + p0*8];
                const short8 kf1 = *(const short8*)&kb[row*64 + (p0^4)*8];
                // one b128 pos read: this lane gets pk4 of key quad*4+(lane&3)
                const floatx4 pkl = pb[kk*16 + quad*4 + (lane & 3)];
                // DPP quad_perm broadcasts -> all 4 r values per lane (VALU pipe)
                float pkx[4], pky[4], pkz[4], pkw[4];
                pkx[0]=qbcast<0>(pkl.x); pky[0]=qbcast<0>(pkl.y); pkz[0]=qbcast<0>(pkl.z); pkw[0]=qbcast<0>(pkl.w);
                pkx[1]=qbcast<1>(pkl.x); pky[1]=qbcast<1>(pkl.y); pkz[1]=qbcast<1>(pkl.z); pkw[1]=qbcast<1>(pkl.w);
                pkx[2]=qbcast<2>(pkl.x); pky[2]=qbcast<2>(pkl.y); pkz[2]=qbcast<2>(pkl.z); pkw[2]=qbcast<2>(pkl.w);
                pkx[3]=qbcast<3>(pkl.x); pky[3]=qbcast<3>(pkl.y); pkz[3]=qbcast<3>(pkl.z); pkw[3]=qbcast<3>(pkl.w);
                #pragma unroll
                for (int qg = 0; qg < 2; qg++) {
                    floatx4 S = {0.f, 0.f, 0.f, 0.f};
                    S = __builtin_amdgcn_mfma_f32_16x16x32_bf16(kf0, qf[qg][0], S, 0, 0, 0);
                    S = __builtin_amdgcn_mfma_f32_16x16x32_bf16(kf1, qf[qg][1], S, 0, 0, 0);
                    const floatx4 pq = pql[qg];
                    float pv[4];
                    #pragma unroll
                    for (int r = 0; r < 4; r++) {
                        const float t = fmaf(pq.x, pkx[r],
                                        fmaf(pq.y, pky[r],
                                        fmaf(pq.z, pkz[r], pq.w + pkw[r])));
                        pv[r] = __builtin_amdgcn_exp2f(S[r] + t);
                    }
                    ph[kk2][qg] = (short4T){ (short)f2bf(pv[0]), (short)f2bf(pv[1]),
                                             (short)f2bf(pv[2]), (short)f2bf(pv[3]) };
                }
            }
            // P A-frags for K=32: position quad*8+j <-> key c2*32 +
            //   (j<4 ? quad*4+j : 16+quad*4+(j-4))
            short8 pf[2];
            #pragma unroll
            for (int qg = 0; qg < 2; qg++)
                pf[qg] = (short8){ ph[0][qg].x, ph[0][qg].y, ph[0][qg].z, ph[0][qg].w,
                                   ph[1][qg].x, ph[1][qg].y, ph[1][qg].z, ph[1][qg].w };
            #pragma unroll
            for (int g = 0; g < 4; g++) {
                const int feat = g*16 + ln;
                const int ci   = c2*4 + (quad >> 1);       // 16B chunk idx (lo keys)
                const int pt   = ci ^ m7;
                const int ho   = (quad & 1) * 4;           // 8B half, in shorts
                const short4T vlo = *(const short4T*)&vb[feat*64 + pt*8 + ho];
                const short4T vhi = *(const short4T*)&vb[feat*64 + (pt^2)*8 + ho];
                const short8 vf = (short8){ vlo.x, vlo.y, vlo.z, vlo.w,
                                            vhi.x, vhi.y, vhi.z, vhi.w };
                O[0][g] = __builtin_amdgcn_mfma_f32_16x16x32_bf16(pf[0], vf, O[0][g], 0, 0, 0);
                O[1][g] = __builtin_amdgcn_mfma_f32_16x16x32_bf16(pf[1], vf, O[1][g], 0, 0, 0);
            }
            Ol[0] = __builtin_amdgcn_mfma_f32_16x16x32_bf16(pf[0], vones, Ol[0], 0, 0, 0);
            Ol[1] = __builtin_amdgcn_mfma_f32_16x16x32_bf16(pf[1], vones, Ol[1], 0, 0, 0);
        }
        buf ^= 1;
    }

    const int hs = h * SEG + seg;
    #pragma unroll
    for (int qg = 0; qg < 2; qg++)
        #pragma unroll
        for (int r = 0; r < 4; r++) {
            const int q = qw + qg*16 + quad*4 + r;
            const size_t base = ((size_t)hs * Nq + q) * 64;
            #pragma unroll
            for (int g = 0; g < 4; g++)
                partO[base + g*16 + ln] = O[qg][g][r];
        }
    if (ln == 0) {
        #pragma unroll
        for (int qg = 0; qg < 2; qg++)
            #pragma unroll
            for (int r = 0; r < 4; r++)
                partL[(size_t)hs * Nq + qw + qg*16 + quad*4 + r] = Ol[qg][r];
    }
}

// ---------------------------------------------------------------------------
// Kernel 3 (fused): merge split-K partials + normalize + project.
//   Per block: 64 queries. ay = O[0:16]; vy[i][v] = O[16+3i+v].
// ---------------------------------------------------------------------------
__global__ __launch_bounds__(256) void finish_kernel(
    const float* __restrict__ partO, const float* __restrict__ partL,
    const float* __restrict__ Wao, const float* __restrict__ Wvo,
    float* __restrict__ out)
{
    __shared__ float T[64 * 65];
    __shared__ float linvS[4][64];
    const int tid  = threadIdx.x;
    const int w    = tid >> 6;
    const int lane = tid & 63;
    const int q0   = blockIdx.x * 64;
    const int n    = q0 + lane;

    // all-head 1/(l*sqrt(N)): thread (w=h, lane=q)
    {
        float s = 0.f;
        #pragma unroll
        for (int sg = 0; sg < SEG; sg++)
            s += partL[(size_t)(w * SEG + sg) * Nq + q0 + lane];
        linvS[w][lane] = 1.0f / (s * 64.0f);
    }
    __syncthreads();

    float aacc[16] = {};
    float vacc[4][3] = {};

    for (int h = 0; h < 4; h++) {
        #pragma unroll
        for (int k = 0; k < 16; k++) {
            const int q = k * 4 + w;
            const int d = lane;
            float acc = 0.f;
            #pragma unroll
            for (int sg = 0; sg < SEG; sg++)
                acc += partO[((size_t)(h * SEG + sg) * Nq + q0 + q) * 64 + d];
            T[d * 65 + q] = acc * linvS[h][q];
        }
        __syncthreads();

        float oh[64];
        #pragma unroll
        for (int d = 0; d < 64; d++)
            oh[d] = T[d * 65 + lane];
        #pragma unroll
        for (int jj = 0; jj < 16; jj++) {
            const int j = w * 16 + jj;
            float acc = aacc[jj];
            #pragma unroll
            for (int i = 0; i < 16; i++)
                acc = fmaf(Wao[(h * 64 + j) * 16 + i], oh[i], acc);
            aacc[jj] = acc;
        }
        #pragma unroll
        for (int jj = 0; jj < 4; jj++) {
            const int j = w * 4 + jj;
            #pragma unroll
            for (int i = 0; i < 16; i++) {
                const float wv = Wvo[(h * 16 + j) * 16 + i];
                vacc[jj][0] = fmaf(wv, oh[16 + 3 * i + 0], vacc[jj][0]);
                vacc[jj][1] = fmaf(wv, oh[16 + 3 * i + 1], vacc[jj][1]);
                vacc[jj][2] = fmaf(wv, oh[16 + 3 * i + 2], vacc[jj][2]);
            }
        }
        __syncthreads();   // T reused next h
    }

    #pragma unroll
    for (int jj = 0; jj < 16; jj++)
        out[(size_t)n * 64 + w * 16 + jj] = aacc[jj];
    float* outv = out + (size_t)Nq * 64;
    #pragma unroll
    for (int jj = 0; jj < 4; jj++)
        #pragma unroll
        for (int v = 0; v < 3; v++)
            outv[((size_t)n * 16 + w * 4 + jj) * 3 + v] = vacc[jj][v];
}

// ---------------------------------------------------------------------------
extern "C" void kernel_launch(void* const* d_in, const int* in_sizes, int n_in,
                              void* d_out, int out_size, void* d_ws, size_t ws_size,
                              hipStream_t stream)
{
    const float* ax    = (const float*)d_in[0];
    const float* vx    = (const float*)d_in[1];
    const float* pos_k = (const float*)d_in[2];
    const float* pos_q = (const float*)d_in[3];
    const float* Waq   = (const float*)d_in[4];
    const float* Wvq   = (const float*)d_in[5];
    const float* Wak   = (const float*)d_in[6];
    const float* Wvk   = (const float*)d_in[7];
    const float* Wav   = (const float*)d_in[8];
    const float* Wvv   = (const float*)d_in[9];
    const float* Wao   = (const float*)d_in[10];
    const float* Wvo   = (const float*)d_in[11];
    float* out = (float*)d_out;

    const size_t MB = 1024 * 1024;
    char* ws = (char*)d_ws;
    // layout: Q(2MB) K(2MB) Vt(2MB) pq4(256K) pk4(256K) partO(33.6MB) partL(512K)
    ushortT* Qg   = (ushortT*)(ws);
    ushortT* Kg   = (ushortT*)(ws + 2*MB);
    ushortT* Vtg  = (ushortT*)(ws + 4*MB);
    floatx4* pq4  = (floatx4*)(ws + 6*MB);
    floatx4* pk4  = (floatx4*)(ws + 6*MB + (size_t)H*Nq*16);
    float*  partO = (float*)(ws + 6*MB + (size_t)2*H*Nq*16);
    float*  partL = (float*)((char*)partO + (size_t)H*SEG*Nq*64*4);

    qkv_kernel<<<dim3(Nq/256, H, 7), 256, 0, stream>>>(
        ax, vx, pos_q, pos_k, Waq, Wvq, Wak, Wvk, Wav, Wvv, Qg, Kg, Vtg, pq4, pk4);
    attn_kernel<<<dim3(Nq/128, H, SEG), 256, 0, stream>>>(
        Qg, Kg, Vtg, pq4, pk4, partO, partL);
    finish_kernel<<<dim3(Nq/64), 256, 0, stream>>>(partO, partL, Wao, Wvo, out);
}

// Round 8
// 159.360 us; speedup vs baseline: 1.4591x; 1.0259x over previous
//
#include <hip/hip_runtime.h>

#define H 4
#define Nq 4096
#define SEG 8
#define NKT ((Nq / SEG) / 64)
#define LOG2E 1.44269504088896340736f

typedef unsigned short ushortT;
typedef __attribute__((ext_vector_type(4))) short short4T;
typedef __attribute__((ext_vector_type(8))) short short8;
typedef __attribute__((ext_vector_type(4))) float floatx4;

// raw pipeline primitives (R4/R7-verified): wait own DMA, barrier without the
// compiler's full vmcnt/lgkmcnt drain (which would also wait the prefetch).
#define WAIT_VM0() asm volatile("s_waitcnt vmcnt(0)" ::: "memory")
#define BARRIER()  asm volatile("s_barrier" ::: "memory")

// round-half-up f32 -> bf16 (inputs finite)
static __device__ __forceinline__ ushortT f2bf(float x) {
    unsigned int u = __builtin_bit_cast(unsigned int, x);
    return (ushortT)((u + 0x8000u) >> 16);
}

// DPP quad_perm broadcast: every lane in each 4-lane group gets slot R's value.
template <int R>
static __device__ __forceinline__ float qbcast(float x) {
    return __builtin_bit_cast(float, __builtin_amdgcn_mov_dpp(
        __builtin_bit_cast(int, x), R * 0x55, 0xf, 0xf, true));
}

// async global->LDS: PER-LANE global address -> LDS uniform base + lane*16.
static __device__ __forceinline__ void gld16(const void* g, void* l) {
    __builtin_amdgcn_global_load_lds(
        reinterpret_cast<const __attribute__((address_space(1))) unsigned int*>(
            reinterpret_cast<unsigned long long>(g)),
        reinterpret_cast<__attribute__((address_space(3))) unsigned int*>(
            static_cast<unsigned int>(reinterpret_cast<unsigned long long>(l))),
        16, 0, 0);
}

// ---------------------------------------------------------------------------
// Kernel 1: QKV projection + stack + vec-activation; z==6 does pos features.
//   V is stored PERMUTED: within each 32-key group, key u = hi*16+quad*4+r
//   lands at slot quad*8+hi*4+r, so the attn PV B-fragment is ONE b128.
// ---------------------------------------------------------------------------
__global__ __launch_bounds__(256) void qkv_kernel(
    const float* __restrict__ ax, const float* __restrict__ vx,
    const float* __restrict__ pos_q, const float* __restrict__ pos_k,
    const float* __restrict__ Waq, const float* __restrict__ Wvq,
    const float* __restrict__ Wak, const float* __restrict__ Wvk,
    const float* __restrict__ Wav, const float* __restrict__ Wvv,
    ushortT* __restrict__ Qg, ushortT* __restrict__ Kg, ushortT* __restrict__ Vtg,
    floatx4* __restrict__ pq4, floatx4* __restrict__ pk4)
{
    const int h = blockIdx.y;
    const int n = blockIdx.x * 256 + threadIdx.x;

    if (blockIdx.z == 6) {      // pos feature branch (block-uniform)
        const float c = LOG2E / (float)(1 << (2 * h));
        {
            const float* p = pos_q + ((size_t)h * Nq + n) * 3;
            const float x = p[0], y = p[1], z = p[2];
            pq4[(size_t)h * Nq + n] = (floatx4){2.f*c*x, 2.f*c*y, 2.f*c*z,
                                                -c * (x*x + y*y + z*z)};
        }
        {
            const float* p = pos_k + ((size_t)h * Nq + n) * 3;
            const float x = p[0], y = p[1], z = p[2];
            pk4[(size_t)h * Nq + n] = (floatx4){x, y, z, -c * (x*x + y*y + z*z)};
        }
        return;
    }

    const int mat   = blockIdx.z >> 1;
    const int chalf = blockIdx.z & 1;
    const int c0    = chalf * 8;

    const float* Wa = (mat == 0 ? Waq : (mat == 1 ? Wak : Wav)) + h * (16 * 64);
    const float* Wv = (mat == 0 ? Wvq : (mat == 1 ? Wvk : Wvv)) + h * (16 * 16);

    float axr[64];
    {
        const floatx4* p = (const floatx4*)(ax + (size_t)n * 64);
        #pragma unroll
        for (int i = 0; i < 16; i++) {
            floatx4 t = p[i];
            axr[4*i+0] = t.x; axr[4*i+1] = t.y; axr[4*i+2] = t.z; axr[4*i+3] = t.w;
        }
    }
    float vxr[48];
    {
        const floatx4* p = (const floatx4*)(vx + (size_t)n * 48);
        #pragma unroll
        for (int i = 0; i < 12; i++) {
            floatx4 t = p[i];
            vxr[4*i+0] = t.x; vxr[4*i+1] = t.y; vxr[4*i+2] = t.z; vxr[4*i+3] = t.w;
        }
    }

    float acca[8] = {};
    float accv[8][3] = {};
    #pragma unroll
    for (int d = 0; d < 64; d++) {
        #pragma unroll
        for (int cc = 0; cc < 8; cc++)
            acca[cc] = fmaf(Wa[(c0 + cc) * 64 + d], axr[d], acca[cc]);
    }
    #pragma unroll
    for (int j = 0; j < 16; j++) {
        #pragma unroll
        for (int cc = 0; cc < 8; cc++) {
            const float w = Wv[(c0 + cc) * 16 + j];
            accv[cc][0] = fmaf(w, vxr[3*j+0], accv[cc][0]);
            accv[cc][1] = fmaf(w, vxr[3*j+1], accv[cc][1]);
            accv[cc][2] = fmaf(w, vxr[3*j+2], accv[cc][2]);
        }
    }

    const float sc_extra = (mat == 0) ? LOG2E : 1.0f;
    __attribute__((aligned(16))) ushortT ob[32];
    #pragma unroll
    for (int cc = 0; cc < 8; cc++) {
        float a = acca[cc], v0 = accv[cc][0], v1 = accv[cc][1], v2 = accv[cc][2];
        float s = 1.0f;
        if (mat < 2) {
            const float nsq = a*a + v0*v0 + v1*v1 + v2*v2;
            s = rsqrtf(sqrtf(1.0f + nsq)) * sc_extra;   // (1+nsq)^(-1/4)
        }
        ob[4*cc+0] = f2bf(a  * s);
        ob[4*cc+1] = f2bf(v0 * s);
        ob[4*cc+2] = f2bf(v1 * s);
        ob[4*cc+3] = f2bf(v2 * s);
    }

    if (mat < 2) {
        ushortT* dst = (mat == 0 ? Qg : Kg) + ((size_t)(h * Nq + n)) * 64 + c0 * 4;
        #pragma unroll
        for (int i = 0; i < 4; i++) ((short8*)dst)[i] = ((const short8*)ob)[i];
    } else {
        // permuted V store: key n -> slot within its 32-key group
        const int u    = n & 31;
        const int slot = ((u >> 2) & 3) * 8 + (u >> 4) * 4 + (u & 3);
        const int np   = (n & ~31) | slot;
        #pragma unroll
        for (int cc = 0; cc < 8; cc++)
            #pragma unroll
            for (int j = 0; j < 4; j++) {
                const int d = c0 * 4 + cc * 4 + j;
                Vtg[((size_t)(h * 64 + d)) * Nq + np] = ob[4*cc+j];
            }
    }
}

// ---------------------------------------------------------------------------
// Kernel 2 (v8): pipelined transposed-S flash attention, 64 q/wave (4 qg),
//   4 waves/block sharing one staged 64-key tile (qtile 256). Double-buffered
//   LDS + raw s_barrier/vmcnt pipeline. K/V/pos DS bytes amortized over 2x
//   the scores of R7; PV B-frag is one b128 (permuted V). P in registers;
//   l via ones-MFMA; pos bias via one b128 + DPP quad_perm broadcasts.
// ---------------------------------------------------------------------------
__global__ __launch_bounds__(256, 2) void attn_kernel(
    const ushortT* __restrict__ Qg, const ushortT* __restrict__ Kg,
    const ushortT* __restrict__ Vtg,
    const floatx4* __restrict__ pq4, const floatx4* __restrict__ pk4,
    float* __restrict__ partO, float* __restrict__ partL)
{
    __shared__ __attribute__((aligned(16))) ushortT kE[2][64 * 64];  // swizzled [key][feat]
    __shared__ __attribute__((aligned(16))) ushortT vE[2][64 * 64];  // swizzled [feat][slot]
    __shared__ __attribute__((aligned(16))) floatx4 posE[2][64];     // pk features

    const int tid  = threadIdx.x;
    const int w    = tid >> 6;
    const int lane = tid & 63;
    const int quad = lane >> 4;
    const int ln   = lane & 15;
    const int m7   = ln & 7;
    const int h    = blockIdx.y;
    const int seg  = blockIdx.z;
    const int qw   = blockIdx.x * 256 + w * 64;     // wave's 64 queries

    // Q fragments (B-operand; Q pre-scaled by log2e) + pq features
    short8 qf[4][2];
    floatx4 pql[4];
    #pragma unroll
    for (int qg = 0; qg < 4; qg++) {
        const short8* qp = (const short8*)(Qg + ((size_t)(h*Nq + qw + qg*16 + ln))*64 + quad*8);
        qf[qg][0] = qp[0];
        qf[qg][1] = qp[4];
        pql[qg]   = pq4[(size_t)h*Nq + qw + qg*16 + ln];
    }

    const ushortT* Khg = Kg  + (size_t)h * Nq * 64;
    const ushortT* Vhg = Vtg + (size_t)h * 64 * Nq;
    const floatx4* ph4 = pk4 + (size_t)h * Nq;

    floatx4 O[4][4] = {};          // [qg][featgroup]: q=quad*4+r, feat=g*16+ln
    floatx4 Ol[4]   = {};          // row-sums l via ones-MFMA
    const short8 vones = {(short)0x3F80, (short)0x3F80, (short)0x3F80, (short)0x3F80,
                          (short)0x3F80, (short)0x3F80, (short)0x3F80, (short)0x3F80};

    // --- DMA stage of one 64-key tile into buffer b (block-cooperative) ---
    auto stage = [&](int k0, int b) {
        #pragma unroll
        for (int i = 0; i < 2; i++) {
            const int cbase = i * 256 + w * 64;     // wave-uniform LDS chunk base
            const int cc    = cbase + lane;         // 0..511
            const int row   = cc >> 3;
            const int part  = (cc & 7) ^ (row & 7); // XOR swizzle
            gld16(Khg + (size_t)(k0 + row)*64 + part*8, (char*)kE[b] + cbase*16);
            gld16(Vhg + (size_t)row*Nq + k0 + part*8, (char*)vE[b] + cbase*16);
        }
        if (w == 3)                                  // wave-uniform branch
            gld16(ph4 + k0 + lane, (char*)posE[b]);  // per-lane global addr
    };

    stage(seg * NKT * 64, 0);
    int buf = 0;

    #pragma unroll 1
    for (int kt = 0; kt < NKT; kt++) {
        WAIT_VM0();       // own DMA(t) complete
        BARRIER();        // all waves' DMA(t) complete; compute(t-1) done
        if (kt + 1 < NKT) stage((seg * NKT + kt + 1) * 64, buf ^ 1);  // overlaps compute(t)

        const ushortT* kb = kE[buf];
        const ushortT* vb = vE[buf];
        const floatx4* pb = posE[buf];

        #pragma unroll
        for (int c2 = 0; c2 < 2; c2++) {
            short4T ph[2][4];      // [kk2][qg] P bf16, keys quad*4+r
            #pragma unroll
            for (int kk2 = 0; kk2 < 2; kk2++) {
                const int kk  = c2*2 + kk2;
                const int row = kk*16 + ln;
                const int p0  = quad ^ m7;
                const short8 kf0 = *(const short8*)&kb[row*64 + p0*8];
                const short8 kf1 = *(const short8*)&kb[row*64 + (p0^4)*8];
                // one b128 pos read: this lane gets pk4 of key quad*4+(lane&3)
                const floatx4 pkl = pb[kk*16 + quad*4 + (lane & 3)];
                // DPP quad_perm broadcasts -> all 4 r values per lane (VALU pipe)
                float pkx[4], pky[4], pkz[4], pkw[4];
                pkx[0]=qbcast<0>(pkl.x); pky[0]=qbcast<0>(pkl.y); pkz[0]=qbcast<0>(pkl.z); pkw[0]=qbcast<0>(pkl.w);
                pkx[1]=qbcast<1>(pkl.x); pky[1]=qbcast<1>(pkl.y); pkz[1]=qbcast<1>(pkl.z); pkw[1]=qbcast<1>(pkl.w);
                pkx[2]=qbcast<2>(pkl.x); pky[2]=qbcast<2>(pkl.y); pkz[2]=qbcast<2>(pkl.z); pkw[2]=qbcast<2>(pkl.w);
                pkx[3]=qbcast<3>(pkl.x); pky[3]=qbcast<3>(pkl.y); pkz[3]=qbcast<3>(pkl.z); pkw[3]=qbcast<3>(pkl.w);
                #pragma unroll
                for (int qg = 0; qg < 4; qg++) {
                    floatx4 S = {0.f, 0.f, 0.f, 0.f};
                    S = __builtin_amdgcn_mfma_f32_16x16x32_bf16(kf0, qf[qg][0], S, 0, 0, 0);
                    S = __builtin_amdgcn_mfma_f32_16x16x32_bf16(kf1, qf[qg][1], S, 0, 0, 0);
                    const floatx4 pq = pql[qg];
                    float pv[4];
                    #pragma unroll
                    for (int r = 0; r < 4; r++) {
                        const float t = fmaf(pq.x, pkx[r],
                                        fmaf(pq.y, pky[r],
                                        fmaf(pq.z, pkz[r], pq.w + pkw[r])));
                        pv[r] = __builtin_amdgcn_exp2f(S[r] + t);
                    }
                    ph[kk2][qg] = (short4T){ (short)f2bf(pv[0]), (short)f2bf(pv[1]),
                                             (short)f2bf(pv[2]), (short)f2bf(pv[3]) };
                }
            }
            // P A-frags for K=32: position quad*8+j <-> key c2*32 +
            //   (j<4 ? quad*4+j : 16+quad*4+(j-4))  == permuted-V slot order
            short8 pf[4];
            #pragma unroll
            for (int qg = 0; qg < 4; qg++)
                pf[qg] = (short8){ ph[0][qg].x, ph[0][qg].y, ph[0][qg].z, ph[0][qg].w,
                                   ph[1][qg].x, ph[1][qg].y, ph[1][qg].z, ph[1][qg].w };
            #pragma unroll
            for (int g = 0; g < 4; g++) {
                const int feat = g*16 + ln;
                const int pt   = (c2*4 + quad) ^ m7;   // permuted-V chunk, swizzled
                const short8 vf = *(const short8*)&vb[feat*64 + pt*8];
                #pragma unroll
                for (int qg = 0; qg < 4; qg++)
                    O[qg][g] = __builtin_amdgcn_mfma_f32_16x16x32_bf16(pf[qg], vf, O[qg][g], 0, 0, 0);
            }
            #pragma unroll
            for (int qg = 0; qg < 4; qg++)
                Ol[qg] = __builtin_amdgcn_mfma_f32_16x16x32_bf16(pf[qg], vones, Ol[qg], 0, 0, 0);
        }
        buf ^= 1;
    }

    const int hs = h * SEG + seg;
    #pragma unroll
    for (int qg = 0; qg < 4; qg++)
        #pragma unroll
        for (int r = 0; r < 4; r++) {
            const int q = qw + qg*16 + quad*4 + r;
            const size_t base = ((size_t)hs * Nq + q) * 64;
            #pragma unroll
            for (int g = 0; g < 4; g++)
                partO[base + g*16 + ln] = O[qg][g][r];
        }
    if (ln == 0) {
        #pragma unroll
        for (int qg = 0; qg < 4; qg++)
            #pragma unroll
            for (int r = 0; r < 4; r++)
                partL[(size_t)hs * Nq + qw + qg*16 + quad*4 + r] = Ol[qg][r];
    }
}

// ---------------------------------------------------------------------------
// Kernel 3 (fused): merge split-K partials + normalize + project.
//   Per block: 64 queries. ay = O[0:16]; vy[i][v] = O[16+3i+v].
// ---------------------------------------------------------------------------
__global__ __launch_bounds__(256) void finish_kernel(
    const float* __restrict__ partO, const float* __restrict__ partL,
    const float* __restrict__ Wao, const float* __restrict__ Wvo,
    float* __restrict__ out)
{
    __shared__ float T[64 * 65];
    __shared__ float linvS[4][64];
    const int tid  = threadIdx.x;
    const int w    = tid >> 6;
    const int lane = tid & 63;
    const int q0   = blockIdx.x * 64;
    const int n    = q0 + lane;

    // all-head 1/(l*sqrt(N)): thread (w=h, lane=q)
    {
        float s = 0.f;
        #pragma unroll
        for (int sg = 0; sg < SEG; sg++)
            s += partL[(size_t)(w * SEG + sg) * Nq + q0 + lane];
        linvS[w][lane] = 1.0f / (s * 64.0f);
    }
    __syncthreads();

    float aacc[16] = {};
    float vacc[4][3] = {};

    for (int h = 0; h < 4; h++) {
        #pragma unroll
        for (int k = 0; k < 16; k++) {
            const int q = k * 4 + w;
            const int d = lane;
            float acc = 0.f;
            #pragma unroll
            for (int sg = 0; sg < SEG; sg++)
                acc += partO[((size_t)(h * SEG + sg) * Nq + q0 + q) * 64 + d];
            T[d * 65 + q] = acc * linvS[h][q];
        }
        __syncthreads();

        float oh[64];
        #pragma unroll
        for (int d = 0; d < 64; d++)
            oh[d] = T[d * 65 + lane];
        #pragma unroll
        for (int jj = 0; jj < 16; jj++) {
            const int j = w * 16 + jj;
            float acc = aacc[jj];
            #pragma unroll
            for (int i = 0; i < 16; i++)
                acc = fmaf(Wao[(h * 64 + j) * 16 + i], oh[i], acc);
            aacc[jj] = acc;
        }
        #pragma unroll
        for (int jj = 0; jj < 4; jj++) {
            const int j = w * 4 + jj;
            #pragma unroll
            for (int i = 0; i < 16; i++) {
                const float wv = Wvo[(h * 16 + j) * 16 + i];
                vacc[jj][0] = fmaf(wv, oh[16 + 3 * i + 0], vacc[jj][0]);
                vacc[jj][1] = fmaf(wv, oh[16 + 3 * i + 1], vacc[jj][1]);
                vacc[jj][2] = fmaf(wv, oh[16 + 3 * i + 2], vacc[jj][2]);
            }
        }
        __syncthreads();   // T reused next h
    }

    #pragma unroll
    for (int jj = 0; jj < 16; jj++)
        out[(size_t)n * 64 + w * 16 + jj] = aacc[jj];
    float* outv = out + (size_t)Nq * 64;
    #pragma unroll
    for (int jj = 0; jj < 4; jj++)
        #pragma unroll
        for (int v = 0; v < 3; v++)
            outv[((size_t)n * 16 + w * 4 + jj) * 3 + v] = vacc[jj][v];
}

// ---------------------------------------------------------------------------
extern "C" void kernel_launch(void* const* d_in, const int* in_sizes, int n_in,
                              void* d_out, int out_size, void* d_ws, size_t ws_size,
                              hipStream_t stream)
{
    const float* ax    = (const float*)d_in[0];
    const float* vx    = (const float*)d_in[1];
    const float* pos_k = (const float*)d_in[2];
    const float* pos_q = (const float*)d_in[3];
    const float* Waq   = (const float*)d_in[4];
    const float* Wvq   = (const float*)d_in[5];
    const float* Wak   = (const float*)d_in[6];
    const float* Wvk   = (const float*)d_in[7];
    const float* Wav   = (const float*)d_in[8];
    const float* Wvv   = (const float*)d_in[9];
    const float* Wao   = (const float*)d_in[10];
    const float* Wvo   = (const float*)d_in[11];
    float* out = (float*)d_out;

    const size_t MB = 1024 * 1024;
    char* ws = (char*)d_ws;
    // layout: Q(2MB) K(2MB) Vt(2MB) pq4(256K) pk4(256K) partO(33.6MB) partL(512K)
    ushortT* Qg   = (ushortT*)(ws);
    ushortT* Kg   = (ushortT*)(ws + 2*MB);
    ushortT* Vtg  = (ushortT*)(ws + 4*MB);
    floatx4* pq4  = (floatx4*)(ws + 6*MB);
    floatx4* pk4  = (floatx4*)(ws + 6*MB + (size_t)H*Nq*16);
    float*  partO = (float*)(ws + 6*MB + (size_t)2*H*Nq*16);
    float*  partL = (float*)((char*)partO + (size_t)H*SEG*Nq*64*4);

    qkv_kernel<<<dim3(Nq/256, H, 7), 256, 0, stream>>>(
        ax, vx, pos_q, pos_k, Waq, Wvq, Wak, Wvk, Wav, Wvv, Qg, Kg, Vtg, pq4, pk4);
    attn_kernel<<<dim3(Nq/256, H, SEG), 256, 0, stream>>>(
        Qg, Kg, Vtg, pq4, pk4, partO, partL);
    finish_kernel<<<dim3(Nq/64), 256, 0, stream>>>(partO, partL, Wao, Wvo, out);
}

// Round 9
// 152.450 us; speedup vs baseline: 1.5252x; 1.0453x over previous
//
#include <hip/hip_runtime.h>

#define H 4
#define Nq 4096
#define SEG 8
#define NKT ((Nq / SEG) / 64)
#define LOG2E 1.44269504088896340736f

typedef unsigned short ushortT;
typedef __attribute__((ext_vector_type(4))) short short4T;
typedef __attribute__((ext_vector_type(8))) short short8;
typedef __attribute__((ext_vector_type(4))) float floatx4;

// raw pipeline primitives (R4/R7/R8-verified): wait own DMA, barrier without
// the compiler's full vmcnt/lgkmcnt drain (which would also wait prefetch).
#define WAIT_VM0() asm volatile("s_waitcnt vmcnt(0)" ::: "memory")
#define BARRIER()  asm volatile("s_barrier" ::: "memory")

// round-half-up f32 -> bf16 (inputs finite)
static __device__ __forceinline__ ushortT f2bf(float x) {
    unsigned int u = __builtin_bit_cast(unsigned int, x);
    return (ushortT)((u + 0x8000u) >> 16);
}
static __device__ __forceinline__ float bf2f(ushortT h) {
    return __builtin_bit_cast(float, (unsigned int)h << 16);
}

// async global->LDS: PER-LANE global address -> LDS uniform base + lane*16.
static __device__ __forceinline__ void gld16(const void* g, void* l) {
    __builtin_amdgcn_global_load_lds(
        reinterpret_cast<const __attribute__((address_space(1))) unsigned int*>(
            reinterpret_cast<unsigned long long>(g)),
        reinterpret_cast<__attribute__((address_space(3))) unsigned int*>(
            static_cast<unsigned int>(reinterpret_cast<unsigned long long>(l))),
        16, 0, 0);
}

// ---------------------------------------------------------------------------
// Kernel 1: QKV projection + stack + vec-activation; z==6 builds the hi/lo
//   split EXTENDED pos features (16 bf16 slots each side) so the attn kernel
//   computes the full logit (QK + distance bias, incl. log2e) inside MFMA:
//   slot table (Q | K), c = log2e/r0sq[h], u=2c*pq, v=pk:
//     3i+0: ux_hi|vx_hi  3i+1: ux_lo|vx_hi  3i+2: ux_hi|vx_lo   (i=x,y,z)
//     9: wq_hi|1  10: wq_lo|1  11: 1|sk_hi  12: 1|sk_lo         (w=-c|pq|^2,
//     13..15: u_lo|v_lo per coord                                s=-c|pk|^2)
//   => dot = 2c*pq.pk - c|pq|^2 - c|pk|^2 exactly (all 4 hi/lo cross terms).
//   V stored PERMUTED (32-key groups, slot quad*8+hi*4+r) for b128 PV frags.
// ---------------------------------------------------------------------------
__global__ __launch_bounds__(256) void qkv_kernel(
    const float* __restrict__ ax, const float* __restrict__ vx,
    const float* __restrict__ pos_q, const float* __restrict__ pos_k,
    const float* __restrict__ Waq, const float* __restrict__ Wvq,
    const float* __restrict__ Wak, const float* __restrict__ Wvk,
    const float* __restrict__ Wav, const float* __restrict__ Wvv,
    ushortT* __restrict__ Qg, ushortT* __restrict__ Kg, ushortT* __restrict__ Vtg,
    ushortT* __restrict__ Qe, ushortT* __restrict__ Ke)
{
    const int h = blockIdx.y;
    const int n = blockIdx.x * 256 + threadIdx.x;

    if (blockIdx.z == 6) {      // extended pos-feature branch (block-uniform)
        const float c = LOG2E / (float)(1 << (2 * h));
        const ushortT one = 0x3F80;
        {   // Q side
            const float* p = pos_q + ((size_t)h * Nq + n) * 3;
            const float x = 2.f*c*p[0], y = 2.f*c*p[1], z = 2.f*c*p[2];
            const float wq = -c * (p[0]*p[0] + p[1]*p[1] + p[2]*p[2]);
            const ushortT xh = f2bf(x), yh = f2bf(y), zh = f2bf(z), wh = f2bf(wq);
            const ushortT xl = f2bf(x - bf2f(xh)), yl = f2bf(y - bf2f(yh));
            const ushortT zl = f2bf(z - bf2f(zh)), wl = f2bf(wq - bf2f(wh));
            __attribute__((aligned(16))) ushortT qe[16] =
                { xh, xl, xh,  yh, yl, yh,  zh, zl, zh,
                  wh, wl, one, one, xl, yl, zl };
            ushortT* dst = Qe + ((size_t)h * Nq + n) * 16;
            ((short8*)dst)[0] = ((const short8*)qe)[0];
            ((short8*)dst)[1] = ((const short8*)qe)[1];
        }
        {   // K side
            const float* p = pos_k + ((size_t)h * Nq + n) * 3;
            const float x = p[0], y = p[1], z = p[2];
            const float sk = -c * (x*x + y*y + z*z);
            const ushortT xh = f2bf(x), yh = f2bf(y), zh = f2bf(z), sh = f2bf(sk);
            const ushortT xl = f2bf(x - bf2f(xh)), yl = f2bf(y - bf2f(yh));
            const ushortT zl = f2bf(z - bf2f(zh)), sl = f2bf(sk - bf2f(sh));
            __attribute__((aligned(16))) ushortT ke[16] =
                { xh, xh, xl,  yh, yh, yl,  zh, zh, zl,
                  one, one, sh, sl, xl, yl, zl };
            ushortT* dst = Ke + ((size_t)h * Nq + n) * 16;
            ((short8*)dst)[0] = ((const short8*)ke)[0];
            ((short8*)dst)[1] = ((const short8*)ke)[1];
        }
        return;
    }

    const int mat   = blockIdx.z >> 1;
    const int chalf = blockIdx.z & 1;
    const int c0    = chalf * 8;

    const float* Wa = (mat == 0 ? Waq : (mat == 1 ? Wak : Wav)) + h * (16 * 64);
    const float* Wv = (mat == 0 ? Wvq : (mat == 1 ? Wvk : Wvv)) + h * (16 * 16);

    float axr[64];
    {
        const floatx4* p = (const floatx4*)(ax + (size_t)n * 64);
        #pragma unroll
        for (int i = 0; i < 16; i++) {
            floatx4 t = p[i];
            axr[4*i+0] = t.x; axr[4*i+1] = t.y; axr[4*i+2] = t.z; axr[4*i+3] = t.w;
        }
    }
    float vxr[48];
    {
        const floatx4* p = (const floatx4*)(vx + (size_t)n * 48);
        #pragma unroll
        for (int i = 0; i < 12; i++) {
            floatx4 t = p[i];
            vxr[4*i+0] = t.x; vxr[4*i+1] = t.y; vxr[4*i+2] = t.z; vxr[4*i+3] = t.w;
        }
    }

    float acca[8] = {};
    float accv[8][3] = {};
    #pragma unroll
    for (int d = 0; d < 64; d++) {
        #pragma unroll
        for (int cc = 0; cc < 8; cc++)
            acca[cc] = fmaf(Wa[(c0 + cc) * 64 + d], axr[d], acca[cc]);
    }
    #pragma unroll
    for (int j = 0; j < 16; j++) {
        #pragma unroll
        for (int cc = 0; cc < 8; cc++) {
            const float w = Wv[(c0 + cc) * 16 + j];
            accv[cc][0] = fmaf(w, vxr[3*j+0], accv[cc][0]);
            accv[cc][1] = fmaf(w, vxr[3*j+1], accv[cc][1]);
            accv[cc][2] = fmaf(w, vxr[3*j+2], accv[cc][2]);
        }
    }

    const float sc_extra = (mat == 0) ? LOG2E : 1.0f;
    __attribute__((aligned(16))) ushortT ob[32];
    #pragma unroll
    for (int cc = 0; cc < 8; cc++) {
        float a = acca[cc], v0 = accv[cc][0], v1 = accv[cc][1], v2 = accv[cc][2];
        float s = 1.0f;
        if (mat < 2) {
            const float nsq = a*a + v0*v0 + v1*v1 + v2*v2;
            s = rsqrtf(sqrtf(1.0f + nsq)) * sc_extra;   // (1+nsq)^(-1/4)
        }
        ob[4*cc+0] = f2bf(a  * s);
        ob[4*cc+1] = f2bf(v0 * s);
        ob[4*cc+2] = f2bf(v1 * s);
        ob[4*cc+3] = f2bf(v2 * s);
    }

    if (mat < 2) {
        ushortT* dst = (mat == 0 ? Qg : Kg) + ((size_t)(h * Nq + n)) * 64 + c0 * 4;
        #pragma unroll
        for (int i = 0; i < 4; i++) ((short8*)dst)[i] = ((const short8*)ob)[i];
    } else {
        // permuted V store: key n -> slot within its 32-key group
        const int u    = n & 31;
        const int slot = ((u >> 2) & 3) * 8 + (u >> 4) * 4 + (u & 3);
        const int np   = (n & ~31) | slot;
        #pragma unroll
        for (int cc = 0; cc < 8; cc++)
            #pragma unroll
            for (int j = 0; j < 4; j++) {
                const int d = c0 * 4 + cc * 4 + j;
                Vtg[((size_t)(h * 64 + d)) * Nq + np] = ob[4*cc+j];
            }
    }
}

// ---------------------------------------------------------------------------
// Kernel 2 (v9): pipelined transposed-S flash attention, 64 q/wave (4 qg),
//   4 waves/block, one staged 64-key tile. Logit = 3 MFMAs (2x QK64 + 1x
//   ext-16 with quads 2/3 zeroed) -- NO per-score bias VALU, no pos staging,
//   no DPP. Then just exp2 + pack. PV b128 (permuted V); l via ones-MFMA.
// ---------------------------------------------------------------------------
__global__ __launch_bounds__(256, 2) void attn_kernel(
    const ushortT* __restrict__ Qg, const ushortT* __restrict__ Kg,
    const ushortT* __restrict__ Vtg,
    const ushortT* __restrict__ Qe, const ushortT* __restrict__ Ke,
    float* __restrict__ partO, float* __restrict__ partL)
{
    __shared__ __attribute__((aligned(16))) ushortT kE[2][64 * 64];   // swizzled [key][feat]
    __shared__ __attribute__((aligned(16))) ushortT vE[2][64 * 64];   // swizzled [feat][slot]
    __shared__ __attribute__((aligned(16))) ushortT kE2[2][64 * 16];  // ext slots [key][16]

    const int tid  = threadIdx.x;
    const int w    = tid >> 6;
    const int lane = tid & 63;
    const int quad = lane >> 4;
    const int ln   = lane & 15;
    const int m7   = ln & 15 & 7;
    const int h    = blockIdx.y;
    const int seg  = blockIdx.z;
    const int qw   = blockIdx.x * 256 + w * 64;     // wave's 64 queries

    const short8 z8 = {0,0,0,0,0,0,0,0};

    // Q fragments (B-operand; Q pre-scaled by log2e) + extended Q features
    short8 qf[4][2];
    short8 qf2[4];
    #pragma unroll
    for (int qg = 0; qg < 4; qg++) {
        const size_t qi = (size_t)h*Nq + qw + qg*16 + ln;
        const short8* qp = (const short8*)(Qg + qi*64 + quad*8);
        qf[qg][0] = qp[0];
        qf[qg][1] = qp[4];
        qf2[qg] = z8;
        if (quad < 2)
            qf2[qg] = *(const short8*)(Qe + qi*16 + quad*8);
    }

    const ushortT* Khg  = Kg  + (size_t)h * Nq * 64;
    const ushortT* Vhg  = Vtg + (size_t)h * 64 * Nq;
    const ushortT* Kehg = Ke  + (size_t)h * Nq * 16;

    floatx4 O[4][4] = {};          // [qg][featgroup]: q=quad*4+r, feat=g*16+ln
    floatx4 Ol[4]   = {};          // row-sums l via ones-MFMA
    const short8 vones = {(short)0x3F80, (short)0x3F80, (short)0x3F80, (short)0x3F80,
                          (short)0x3F80, (short)0x3F80, (short)0x3F80, (short)0x3F80};

    // --- DMA stage of one 64-key tile into buffer b (block-cooperative) ---
    auto stage = [&](int k0, int b) {
        #pragma unroll
        for (int i = 0; i < 2; i++) {
            const int cbase = i * 256 + w * 64;     // wave-uniform LDS chunk base
            const int cc    = cbase + lane;         // 0..511
            const int row   = cc >> 3;
            const int part  = (cc & 7) ^ (row & 7); // XOR swizzle
            gld16(Khg + (size_t)(k0 + row)*64 + part*8, (char*)kE[b] + cbase*16);
            gld16(Vhg + (size_t)row*Nq + k0 + part*8, (char*)vE[b] + cbase*16);
        }
        // ext slots: 128 chunks of 16B, 32 per wave (lanes 0..31 active)
        if (lane < 32) {
            const int cc = w * 32 + lane;           // 0..127
            gld16(Kehg + (size_t)(k0 + (cc >> 1))*16 + (cc & 1)*8,
                  (char*)kE2[b] + w * 512);
        }
    };

    stage(seg * NKT * 64, 0);
    int buf = 0;

    #pragma unroll 1
    for (int kt = 0; kt < NKT; kt++) {
        WAIT_VM0();       // own DMA(t) complete
        BARRIER();        // all waves' DMA(t) complete; compute(t-1) done
        if (kt + 1 < NKT) stage((seg * NKT + kt + 1) * 64, buf ^ 1);  // overlaps compute(t)

        const ushortT* kb  = kE[buf];
        const ushortT* vb  = vE[buf];
        const ushortT* kb2 = kE2[buf];

        #pragma unroll
        for (int c2 = 0; c2 < 2; c2++) {
            short4T ph[2][4];      // [kk2][qg] P bf16, keys quad*4+r
            #pragma unroll
            for (int kk2 = 0; kk2 < 2; kk2++) {
                const int kk  = c2*2 + kk2;
                const int row = kk*16 + ln;
                const int p0  = quad ^ m7;
                const short8 kf0 = *(const short8*)&kb[row*64 + p0*8];
                const short8 kf1 = *(const short8*)&kb[row*64 + (p0^4)*8];
                short8 kf2 = z8;
                if (quad < 2)
                    kf2 = *(const short8*)&kb2[row*16 + quad*8];
                #pragma unroll
                for (int qg = 0; qg < 4; qg++) {
                    floatx4 S = {0.f, 0.f, 0.f, 0.f};
                    S = __builtin_amdgcn_mfma_f32_16x16x32_bf16(kf0, qf[qg][0], S, 0, 0, 0);
                    S = __builtin_amdgcn_mfma_f32_16x16x32_bf16(kf1, qf[qg][1], S, 0, 0, 0);
                    S = __builtin_amdgcn_mfma_f32_16x16x32_bf16(kf2, qf2[qg],  S, 0, 0, 0);
                    // S already includes the full distance bias (log2-domain)
                    const float p0v = __builtin_amdgcn_exp2f(S[0]);
                    const float p1v = __builtin_amdgcn_exp2f(S[1]);
                    const float p2v = __builtin_amdgcn_exp2f(S[2]);
                    const float p3v = __builtin_amdgcn_exp2f(S[3]);
                    ph[kk2][qg] = (short4T){ (short)f2bf(p0v), (short)f2bf(p1v),
                                             (short)f2bf(p2v), (short)f2bf(p3v) };
                }
            }
            // P A-frags for K=32: position quad*8+j <-> key c2*32 +
            //   (j<4 ? quad*4+j : 16+quad*4+(j-4))  == permuted-V slot order
            short8 pf[4];
            #pragma unroll
            for (int qg = 0; qg < 4; qg++)
                pf[qg] = (short8){ ph[0][qg].x, ph[0][qg].y, ph[0][qg].z, ph[0][qg].w,
                                   ph[1][qg].x, ph[1][qg].y, ph[1][qg].z, ph[1][qg].w };
            #pragma unroll
            for (int g = 0; g < 4; g++) {
                const int feat = g*16 + ln;
                const int pt   = (c2*4 + quad) ^ m7;   // permuted-V chunk, swizzled
                const short8 vf = *(const short8*)&vb[feat*64 + pt*8];
                #pragma unroll
                for (int qg = 0; qg < 4; qg++)
                    O[qg][g] = __builtin_amdgcn_mfma_f32_16x16x32_bf16(pf[qg], vf, O[qg][g], 0, 0, 0);
            }
            #pragma unroll
            for (int qg = 0; qg < 4; qg++)
                Ol[qg] = __builtin_amdgcn_mfma_f32_16x16x32_bf16(pf[qg], vones, Ol[qg], 0, 0, 0);
        }
        buf ^= 1;
    }

    const int hs = h * SEG + seg;
    #pragma unroll
    for (int qg = 0; qg < 4; qg++)
        #pragma unroll
        for (int r = 0; r < 4; r++) {
            const int q = qw + qg*16 + quad*4 + r;
            const size_t base = ((size_t)hs * Nq + q) * 64;
            #pragma unroll
            for (int g = 0; g < 4; g++)
                partO[base + g*16 + ln] = O[qg][g][r];
        }
    if (ln == 0) {
        #pragma unroll
        for (int qg = 0; qg < 4; qg++)
            #pragma unroll
            for (int r = 0; r < 4; r++)
                partL[(size_t)hs * Nq + qw + qg*16 + quad*4 + r] = Ol[qg][r];
    }
}

// ---------------------------------------------------------------------------
// Kernel 3 (fused): merge split-K partials + normalize + project.
//   Per block: 64 queries. ay = O[0:16]; vy[i][v] = O[16+3i+v].
// ---------------------------------------------------------------------------
__global__ __launch_bounds__(256) void finish_kernel(
    const float* __restrict__ partO, const float* __restrict__ partL,
    const float* __restrict__ Wao, const float* __restrict__ Wvo,
    float* __restrict__ out)
{
    __shared__ float T[64 * 65];
    __shared__ float linvS[4][64];
    const int tid  = threadIdx.x;
    const int w    = tid >> 6;
    const int lane = tid & 63;
    const int q0   = blockIdx.x * 64;
    const int n    = q0 + lane;

    // all-head 1/(l*sqrt(N)): thread (w=h, lane=q)
    {
        float s = 0.f;
        #pragma unroll
        for (int sg = 0; sg < SEG; sg++)
            s += partL[(size_t)(w * SEG + sg) * Nq + q0 + lane];
        linvS[w][lane] = 1.0f / (s * 64.0f);
    }
    __syncthreads();

    float aacc[16] = {};
    float vacc[4][3] = {};

    for (int h = 0; h < 4; h++) {
        #pragma unroll
        for (int k = 0; k < 16; k++) {
            const int q = k * 4 + w;
            const int d = lane;
            float acc = 0.f;
            #pragma unroll
            for (int sg = 0; sg < SEG; sg++)
                acc += partO[((size_t)(h * SEG + sg) * Nq + q0 + q) * 64 + d];
            T[d * 65 + q] = acc * linvS[h][q];
        }
        __syncthreads();

        float oh[64];
        #pragma unroll
        for (int d = 0; d < 64; d++)
            oh[d] = T[d * 65 + lane];
        #pragma unroll
        for (int jj = 0; jj < 16; jj++) {
            const int j = w * 16 + jj;
            float acc = aacc[jj];
            #pragma unroll
            for (int i = 0; i < 16; i++)
                acc = fmaf(Wao[(h * 64 + j) * 16 + i], oh[i], acc);
            aacc[jj] = acc;
        }
        #pragma unroll
        for (int jj = 0; jj < 4; jj++) {
            const int j = w * 4 + jj;
            #pragma unroll
            for (int i = 0; i < 16; i++) {
                const float wv = Wvo[(h * 16 + j) * 16 + i];
                vacc[jj][0] = fmaf(wv, oh[16 + 3 * i + 0], vacc[jj][0]);
                vacc[jj][1] = fmaf(wv, oh[16 + 3 * i + 1], vacc[jj][1]);
                vacc[jj][2] = fmaf(wv, oh[16 + 3 * i + 2], vacc[jj][2]);
            }
        }
        __syncthreads();   // T reused next h
    }

    #pragma unroll
    for (int jj = 0; jj < 16; jj++)
        out[(size_t)n * 64 + w * 16 + jj] = aacc[jj];
    float* outv = out + (size_t)Nq * 64;
    #pragma unroll
    for (int jj = 0; jj < 4; jj++)
        #pragma unroll
        for (int v = 0; v < 3; v++)
            outv[((size_t)n * 16 + w * 4 + jj) * 3 + v] = vacc[jj][v];
}

// ---------------------------------------------------------------------------
extern "C" void kernel_launch(void* const* d_in, const int* in_sizes, int n_in,
                              void* d_out, int out_size, void* d_ws, size_t ws_size,
                              hipStream_t stream)
{
    const float* ax    = (const float*)d_in[0];
    const float* vx    = (const float*)d_in[1];
    const float* pos_k = (const float*)d_in[2];
    const float* pos_q = (const float*)d_in[3];
    const float* Waq   = (const float*)d_in[4];
    const float* Wvq   = (const float*)d_in[5];
    const float* Wak   = (const float*)d_in[6];
    const float* Wvk   = (const float*)d_in[7];
    const float* Wav   = (const float*)d_in[8];
    const float* Wvv   = (const float*)d_in[9];
    const float* Wao   = (const float*)d_in[10];
    const float* Wvo   = (const float*)d_in[11];
    float* out = (float*)d_out;

    const size_t MB = 1024 * 1024;
    char* ws = (char*)d_ws;
    // layout: Q(2MB) K(2MB) Vt(2MB) Qe(512K) Ke(512K) partO(33.6MB) partL(512K)
    ushortT* Qg   = (ushortT*)(ws);
    ushortT* Kg   = (ushortT*)(ws + 2*MB);
    ushortT* Vtg  = (ushortT*)(ws + 4*MB);
    ushortT* Qe   = (ushortT*)(ws + 6*MB);
    ushortT* Ke   = (ushortT*)(ws + 6*MB + (size_t)H*Nq*16*2);
    float*  partO = (float*)(ws + 6*MB + (size_t)2*H*Nq*16*2);
    float*  partL = (float*)((char*)partO + (size_t)H*SEG*Nq*64*4);

    qkv_kernel<<<dim3(Nq/256, H, 7), 256, 0, stream>>>(
        ax, vx, pos_q, pos_k, Waq, Wvq, Wak, Wvk, Wav, Wvv, Qg, Kg, Vtg, Qe, Ke);
    attn_kernel<<<dim3(Nq/256, H, SEG), 256, 0, stream>>>(
        Qg, Kg, Vtg, Qe, Ke, partO, partL);
    finish_kernel<<<dim3(Nq/64), 256, 0, stream>>>(partO, partL, Wao, Wvo, out);
}

// Round 10
// 121.410 us; speedup vs baseline: 1.9152x; 1.2557x over previous
//
#include <hip/hip_runtime.h>

#define H 4
#define Nq 4096
#define SEG 8
#define NKT ((Nq / SEG) / 64)
#define LOG2E 1.44269504088896340736f

typedef unsigned short ushortT;
typedef __attribute__((ext_vector_type(4))) short short4T;
typedef __attribute__((ext_vector_type(8))) short short8;
typedef __attribute__((ext_vector_type(4))) float floatx4;

// raw pipeline primitives (R4/R7/R8/R9-verified)
#define WAIT_VM0() asm volatile("s_waitcnt vmcnt(0)" ::: "memory")
#define BARRIER()  asm volatile("s_barrier" ::: "memory")

// round-half-up f32 -> bf16 (inputs finite)
static __device__ __forceinline__ ushortT f2bf(float x) {
    unsigned int u = __builtin_bit_cast(unsigned int, x);
    return (ushortT)((u + 0x8000u) >> 16);
}
static __device__ __forceinline__ float bf2f(ushortT h) {
    return __builtin_bit_cast(float, (unsigned int)h << 16);
}

// async global->LDS: PER-LANE global address -> LDS uniform base + lane*16.
static __device__ __forceinline__ void gld16(const void* g, void* l) {
    __builtin_amdgcn_global_load_lds(
        reinterpret_cast<const __attribute__((address_space(1))) unsigned int*>(
            reinterpret_cast<unsigned long long>(g)),
        reinterpret_cast<__attribute__((address_space(3))) unsigned int*>(
            static_cast<unsigned int>(reinterpret_cast<unsigned long long>(l))),
        16, 0, 0);
}

// ---------------------------------------------------------------------------
// Kernel 1 (unchanged from R9): QKV projection + stack + vec-activation;
//   z==6 builds hi/lo split EXTENDED pos features (16 bf16 slots per side) so
//   attn computes the full logit (QK + distance bias, incl. log2e) in MFMA.
//   V stored PERMUTED (32-key groups, slot quad*8+hi*4+r) for b128 PV frags.
// ---------------------------------------------------------------------------
__global__ __launch_bounds__(256) void qkv_kernel(
    const float* __restrict__ ax, const float* __restrict__ vx,
    const float* __restrict__ pos_q, const float* __restrict__ pos_k,
    const float* __restrict__ Waq, const float* __restrict__ Wvq,
    const float* __restrict__ Wak, const float* __restrict__ Wvk,
    const float* __restrict__ Wav, const float* __restrict__ Wvv,
    ushortT* __restrict__ Qg, ushortT* __restrict__ Kg, ushortT* __restrict__ Vtg,
    ushortT* __restrict__ Qe, ushortT* __restrict__ Ke)
{
    const int h = blockIdx.y;
    const int n = blockIdx.x * 256 + threadIdx.x;

    if (blockIdx.z == 6) {      // extended pos-feature branch (block-uniform)
        const float c = LOG2E / (float)(1 << (2 * h));
        const ushortT one = 0x3F80;
        {   // Q side
            const float* p = pos_q + ((size_t)h * Nq + n) * 3;
            const float x = 2.f*c*p[0], y = 2.f*c*p[1], z = 2.f*c*p[2];
            const float wq = -c * (p[0]*p[0] + p[1]*p[1] + p[2]*p[2]);
            const ushortT xh = f2bf(x), yh = f2bf(y), zh = f2bf(z), wh = f2bf(wq);
            const ushortT xl = f2bf(x - bf2f(xh)), yl = f2bf(y - bf2f(yh));
            const ushortT zl = f2bf(z - bf2f(zh)), wl = f2bf(wq - bf2f(wh));
            __attribute__((aligned(16))) ushortT qe[16] =
                { xh, xl, xh,  yh, yl, yh,  zh, zl, zh,
                  wh, wl, one, one, xl, yl, zl };
            ushortT* dst = Qe + ((size_t)h * Nq + n) * 16;
            ((short8*)dst)[0] = ((const short8*)qe)[0];
            ((short8*)dst)[1] = ((const short8*)qe)[1];
        }
        {   // K side
            const float* p = pos_k + ((size_t)h * Nq + n) * 3;
            const float x = p[0], y = p[1], z = p[2];
            const float sk = -c * (x*x + y*y + z*z);
            const ushortT xh = f2bf(x), yh = f2bf(y), zh = f2bf(z), sh = f2bf(sk);
            const ushortT xl = f2bf(x - bf2f(xh)), yl = f2bf(y - bf2f(yh));
            const ushortT zl = f2bf(z - bf2f(zh)), sl = f2bf(sk - bf2f(sh));
            __attribute__((aligned(16))) ushortT ke[16] =
                { xh, xh, xl,  yh, yh, yl,  zh, zh, zl,
                  one, one, sh, sl, xl, yl, zl };
            ushortT* dst = Ke + ((size_t)h * Nq + n) * 16;
            ((short8*)dst)[0] = ((const short8*)ke)[0];
            ((short8*)dst)[1] = ((const short8*)ke)[1];
        }
        return;
    }

    const int mat   = blockIdx.z >> 1;
    const int chalf = blockIdx.z & 1;
    const int c0    = chalf * 8;

    const float* Wa = (mat == 0 ? Waq : (mat == 1 ? Wak : Wav)) + h * (16 * 64);
    const float* Wv = (mat == 0 ? Wvq : (mat == 1 ? Wvk : Wvv)) + h * (16 * 16);

    float axr[64];
    {
        const floatx4* p = (const floatx4*)(ax + (size_t)n * 64);
        #pragma unroll
        for (int i = 0; i < 16; i++) {
            floatx4 t = p[i];
            axr[4*i+0] = t.x; axr[4*i+1] = t.y; axr[4*i+2] = t.z; axr[4*i+3] = t.w;
        }
    }
    float vxr[48];
    {
        const floatx4* p = (const floatx4*)(vx + (size_t)n * 48);
        #pragma unroll
        for (int i = 0; i < 12; i++) {
            floatx4 t = p[i];
            vxr[4*i+0] = t.x; vxr[4*i+1] = t.y; vxr[4*i+2] = t.z; vxr[4*i+3] = t.w;
        }
    }

    float acca[8] = {};
    float accv[8][3] = {};
    #pragma unroll
    for (int d = 0; d < 64; d++) {
        #pragma unroll
        for (int cc = 0; cc < 8; cc++)
            acca[cc] = fmaf(Wa[(c0 + cc) * 64 + d], axr[d], acca[cc]);
    }
    #pragma unroll
    for (int j = 0; j < 16; j++) {
        #pragma unroll
        for (int cc = 0; cc < 8; cc++) {
            const float w = Wv[(c0 + cc) * 16 + j];
            accv[cc][0] = fmaf(w, vxr[3*j+0], accv[cc][0]);
            accv[cc][1] = fmaf(w, vxr[3*j+1], accv[cc][1]);
            accv[cc][2] = fmaf(w, vxr[3*j+2], accv[cc][2]);
        }
    }

    const float sc_extra = (mat == 0) ? LOG2E : 1.0f;
    __attribute__((aligned(16))) ushortT ob[32];
    #pragma unroll
    for (int cc = 0; cc < 8; cc++) {
        float a = acca[cc], v0 = accv[cc][0], v1 = accv[cc][1], v2 = accv[cc][2];
        float s = 1.0f;
        if (mat < 2) {
            const float nsq = a*a + v0*v0 + v1*v1 + v2*v2;
            s = rsqrtf(sqrtf(1.0f + nsq)) * sc_extra;   // (1+nsq)^(-1/4)
        }
        ob[4*cc+0] = f2bf(a  * s);
        ob[4*cc+1] = f2bf(v0 * s);
        ob[4*cc+2] = f2bf(v1 * s);
        ob[4*cc+3] = f2bf(v2 * s);
    }

    if (mat < 2) {
        ushortT* dst = (mat == 0 ? Qg : Kg) + ((size_t)(h * Nq + n)) * 64 + c0 * 4;
        #pragma unroll
        for (int i = 0; i < 4; i++) ((short8*)dst)[i] = ((const short8*)ob)[i];
    } else {
        // permuted V store: key n -> slot within its 32-key group
        const int u    = n & 31;
        const int slot = ((u >> 2) & 3) * 8 + (u >> 4) * 4 + (u & 3);
        const int np   = (n & ~31) | slot;
        #pragma unroll
        for (int cc = 0; cc < 8; cc++)
            #pragma unroll
            for (int j = 0; j < 4; j++) {
                const int d = c0 * 4 + cc * 4 + j;
                Vtg[((size_t)(h * 64 + d)) * Nq + np] = ob[4*cc+j];
            }
    }
}

// ---------------------------------------------------------------------------
// Kernel 2 (unchanged from R9): pipelined transposed-S flash attention,
//   64 q/wave (4 qg), 4 waves/block, one staged 64-key tile. Logit = 3 MFMAs
//   (2x QK64 + 1x ext-16, quads 2/3 zeroed). PV b128 (permuted V); l via
//   ones-MFMA; raw s_barrier/vmcnt double-buffer pipeline.
// ---------------------------------------------------------------------------
__global__ __launch_bounds__(256, 2) void attn_kernel(
    const ushortT* __restrict__ Qg, const ushortT* __restrict__ Kg,
    const ushortT* __restrict__ Vtg,
    const ushortT* __restrict__ Qe, const ushortT* __restrict__ Ke,
    float* __restrict__ partO, float* __restrict__ partL)
{
    __shared__ __attribute__((aligned(16))) ushortT kE[2][64 * 64];   // swizzled [key][feat]
    __shared__ __attribute__((aligned(16))) ushortT vE[2][64 * 64];   // swizzled [feat][slot]
    __shared__ __attribute__((aligned(16))) ushortT kE2[2][64 * 16];  // ext slots [key][16]

    const int tid  = threadIdx.x;
    const int w    = tid >> 6;
    const int lane = tid & 63;
    const int quad = lane >> 4;
    const int ln   = lane & 15;
    const int m7   = ln & 7;
    const int h    = blockIdx.y;
    const int seg  = blockIdx.z;
    const int qw   = blockIdx.x * 256 + w * 64;     // wave's 64 queries

    const short8 z8 = {0,0,0,0,0,0,0,0};

    // Q fragments (B-operand; Q pre-scaled by log2e) + extended Q features
    short8 qf[4][2];
    short8 qf2[4];
    #pragma unroll
    for (int qg = 0; qg < 4; qg++) {
        const size_t qi = (size_t)h*Nq + qw + qg*16 + ln;
        const short8* qp = (const short8*)(Qg + qi*64 + quad*8);
        qf[qg][0] = qp[0];
        qf[qg][1] = qp[4];
        qf2[qg] = z8;
        if (quad < 2)
            qf2[qg] = *(const short8*)(Qe + qi*16 + quad*8);
    }

    const ushortT* Khg  = Kg  + (size_t)h * Nq * 64;
    const ushortT* Vhg  = Vtg + (size_t)h * 64 * Nq;
    const ushortT* Kehg = Ke  + (size_t)h * Nq * 16;

    floatx4 O[4][4] = {};          // [qg][featgroup]: q=quad*4+r, feat=g*16+ln
    floatx4 Ol[4]   = {};          // row-sums l via ones-MFMA
    const short8 vones = {(short)0x3F80, (short)0x3F80, (short)0x3F80, (short)0x3F80,
                          (short)0x3F80, (short)0x3F80, (short)0x3F80, (short)0x3F80};

    // --- DMA stage of one 64-key tile into buffer b (block-cooperative) ---
    auto stage = [&](int k0, int b) {
        #pragma unroll
        for (int i = 0; i < 2; i++) {
            const int cbase = i * 256 + w * 64;     // wave-uniform LDS chunk base
            const int cc    = cbase + lane;         // 0..511
            const int row   = cc >> 3;
            const int part  = (cc & 7) ^ (row & 7); // XOR swizzle
            gld16(Khg + (size_t)(k0 + row)*64 + part*8, (char*)kE[b] + cbase*16);
            gld16(Vhg + (size_t)row*Nq + k0 + part*8, (char*)vE[b] + cbase*16);
        }
        // ext slots: 128 chunks of 16B, 32 per wave (lanes 0..31 active)
        if (lane < 32) {
            const int cc = w * 32 + lane;           // 0..127
            gld16(Kehg + (size_t)(k0 + (cc >> 1))*16 + (cc & 1)*8,
                  (char*)kE2[b] + w * 512);
        }
    };

    stage(seg * NKT * 64, 0);
    int buf = 0;

    #pragma unroll 1
    for (int kt = 0; kt < NKT; kt++) {
        WAIT_VM0();       // own DMA(t) complete
        BARRIER();        // all waves' DMA(t) complete; compute(t-1) done
        if (kt + 1 < NKT) stage((seg * NKT + kt + 1) * 64, buf ^ 1);  // overlaps compute(t)

        const ushortT* kb  = kE[buf];
        const ushortT* vb  = vE[buf];
        const ushortT* kb2 = kE2[buf];

        #pragma unroll
        for (int c2 = 0; c2 < 2; c2++) {
            short4T ph[2][4];      // [kk2][qg] P bf16, keys quad*4+r
            #pragma unroll
            for (int kk2 = 0; kk2 < 2; kk2++) {
                const int kk  = c2*2 + kk2;
                const int row = kk*16 + ln;
                const int p0  = quad ^ m7;
                const short8 kf0 = *(const short8*)&kb[row*64 + p0*8];
                const short8 kf1 = *(const short8*)&kb[row*64 + (p0^4)*8];
                short8 kf2 = z8;
                if (quad < 2)
                    kf2 = *(const short8*)&kb2[row*16 + quad*8];
                #pragma unroll
                for (int qg = 0; qg < 4; qg++) {
                    floatx4 S = {0.f, 0.f, 0.f, 0.f};
                    S = __builtin_amdgcn_mfma_f32_16x16x32_bf16(kf0, qf[qg][0], S, 0, 0, 0);
                    S = __builtin_amdgcn_mfma_f32_16x16x32_bf16(kf1, qf[qg][1], S, 0, 0, 0);
                    S = __builtin_amdgcn_mfma_f32_16x16x32_bf16(kf2, qf2[qg],  S, 0, 0, 0);
                    // S already includes the full distance bias (log2-domain)
                    const float p0v = __builtin_amdgcn_exp2f(S[0]);
                    const float p1v = __builtin_amdgcn_exp2f(S[1]);
                    const float p2v = __builtin_amdgcn_exp2f(S[2]);
                    const float p3v = __builtin_amdgcn_exp2f(S[3]);
                    ph[kk2][qg] = (short4T){ (short)f2bf(p0v), (short)f2bf(p1v),
                                             (short)f2bf(p2v), (short)f2bf(p3v) };
                }
            }
            // P A-frags for K=32: position quad*8+j <-> key c2*32 +
            //   (j<4 ? quad*4+j : 16+quad*4+(j-4))  == permuted-V slot order
            short8 pf[4];
            #pragma unroll
            for (int qg = 0; qg < 4; qg++)
                pf[qg] = (short8){ ph[0][qg].x, ph[0][qg].y, ph[0][qg].z, ph[0][qg].w,
                                   ph[1][qg].x, ph[1][qg].y, ph[1][qg].z, ph[1][qg].w };
            #pragma unroll
            for (int g = 0; g < 4; g++) {
                const int feat = g*16 + ln;
                const int pt   = (c2*4 + quad) ^ m7;   // permuted-V chunk, swizzled
                const short8 vf = *(const short8*)&vb[feat*64 + pt*8];
                #pragma unroll
                for (int qg = 0; qg < 4; qg++)
                    O[qg][g] = __builtin_amdgcn_mfma_f32_16x16x32_bf16(pf[qg], vf, O[qg][g], 0, 0, 0);
            }
            #pragma unroll
            for (int qg = 0; qg < 4; qg++)
                Ol[qg] = __builtin_amdgcn_mfma_f32_16x16x32_bf16(pf[qg], vones, Ol[qg], 0, 0, 0);
        }
        buf ^= 1;
    }

    const int hs = h * SEG + seg;
    #pragma unroll
    for (int qg = 0; qg < 4; qg++)
        #pragma unroll
        for (int r = 0; r < 4; r++) {
            const int q = qw + qg*16 + quad*4 + r;
            const size_t base = ((size_t)hs * Nq + q) * 64;
            #pragma unroll
            for (int g = 0; g < 4; g++)
                partO[base + g*16 + ln] = O[qg][g][r];
        }
    if (ln == 0) {
        #pragma unroll
        for (int qg = 0; qg < 4; qg++)
            #pragma unroll
            for (int r = 0; r < 4; r++)
                partL[(size_t)hs * Nq + qw + qg*16 + quad*4 + r] = Ol[qg][r];
    }
}

// ---------------------------------------------------------------------------
// Kernel 3 (v10): merge + normalize + project, 4x PARALLELISM (256 blocks of
//   16 queries; 1024 waves = every SIMD). Merge: 4 (d,q) elems/thread,
//   coalesced in d. Project: thread -> (q = tid&15, group g = tid>>4);
//   g<16 handles a-outputs j=4g..4g+3 and v-channel g. T reads are 4-way
//   broadcast (bank-clean, stride 17). ay = O[0:16]; vy[i][v] = O[16+3i+v].
// ---------------------------------------------------------------------------
__global__ __launch_bounds__(256) void finish_kernel(
    const float* __restrict__ partO, const float* __restrict__ partL,
    const float* __restrict__ Wao, const float* __restrict__ Wvo,
    float* __restrict__ out)
{
    __shared__ float T[64 * 17];
    __shared__ float linvS[4][16];
    const int tid = threadIdx.x;
    const int q0  = blockIdx.x * 16;

    if (tid < 64) {
        const int hh = tid >> 4, qq = tid & 15;
        float s = 0.f;
        #pragma unroll
        for (int sg = 0; sg < SEG; sg++)
            s += partL[(size_t)(hh * SEG + sg) * Nq + q0 + qq];
        linvS[hh][qq] = 1.0f / (s * 64.0f);    // 1/(l*sqrt(N))
    }
    __syncthreads();

    const int qT = tid & 15;      // project-phase query (n = q0 + qT)
    const int g  = tid >> 4;      // project-phase output group 0..15
    float aacc[4] = {};
    float vacc[3] = {};

    for (int h = 0; h < 4; h++) {
        // merge phase: 1024 (d,q) elements, 4 per thread, coalesced in d
        #pragma unroll
        for (int i = 0; i < 4; i++) {
            const int idx = tid + i * 256;
            const int d = idx & 63;
            const int q = idx >> 6;
            float acc = 0.f;
            #pragma unroll
            for (int sg = 0; sg < SEG; sg++)
                acc += partO[((size_t)(h * SEG + sg) * Nq + q0 + q) * 64 + d];
            T[d * 17 + q] = acc * linvS[h][q];
        }
        __syncthreads();

        // project phase
        float oh[64];
        #pragma unroll
        for (int d = 0; d < 64; d++)
            oh[d] = T[d * 17 + qT];
        #pragma unroll
        for (int jj = 0; jj < 4; jj++) {
            const int j = g * 4 + jj;
            float acc = aacc[jj];
            #pragma unroll
            for (int i = 0; i < 16; i++)
                acc = fmaf(Wao[(h * 64 + j) * 16 + i], oh[i], acc);
            aacc[jj] = acc;
        }
        #pragma unroll
        for (int i = 0; i < 16; i++) {
            const float wv = Wvo[(h * 16 + g) * 16 + i];
            vacc[0] = fmaf(wv, oh[16 + 3 * i + 0], vacc[0]);
            vacc[1] = fmaf(wv, oh[16 + 3 * i + 1], vacc[1]);
            vacc[2] = fmaf(wv, oh[16 + 3 * i + 2], vacc[2]);
        }
        __syncthreads();   // T reused next h
    }

    const int n = q0 + qT;
    #pragma unroll
    for (int jj = 0; jj < 4; jj++)
        out[(size_t)n * 64 + g * 4 + jj] = aacc[jj];
    float* outv = out + (size_t)Nq * 64;
    #pragma unroll
    for (int c = 0; c < 3; c++)
        outv[((size_t)n * 16 + g) * 3 + c] = vacc[c];
}

// ---------------------------------------------------------------------------
extern "C" void kernel_launch(void* const* d_in, const int* in_sizes, int n_in,
                              void* d_out, int out_size, void* d_ws, size_t ws_size,
                              hipStream_t stream)
{
    const float* ax    = (const float*)d_in[0];
    const float* vx    = (const float*)d_in[1];
    const float* pos_k = (const float*)d_in[2];
    const float* pos_q = (const float*)d_in[3];
    const float* Waq   = (const float*)d_in[4];
    const float* Wvq   = (const float*)d_in[5];
    const float* Wak   = (const float*)d_in[6];
    const float* Wvk   = (const float*)d_in[7];
    const float* Wav   = (const float*)d_in[8];
    const float* Wvv   = (const float*)d_in[9];
    const float* Wao   = (const float*)d_in[10];
    const float* Wvo   = (const float*)d_in[11];
    float* out = (float*)d_out;

    const size_t MB = 1024 * 1024;
    char* ws = (char*)d_ws;
    // layout: Q(2MB) K(2MB) Vt(2MB) Qe(512K) Ke(512K) partO(33.6MB) partL(512K)
    ushortT* Qg   = (ushortT*)(ws);
    ushortT* Kg   = (ushortT*)(ws + 2*MB);
    ushortT* Vtg  = (ushortT*)(ws + 4*MB);
    ushortT* Qe   = (ushortT*)(ws + 6*MB);
    ushortT* Ke   = (ushortT*)(ws + 6*MB + (size_t)H*Nq*16*2);
    float*  partO = (float*)(ws + 6*MB + (size_t)2*H*Nq*16*2);
    float*  partL = (float*)((char*)partO + (size_t)H*SEG*Nq*64*4);

    qkv_kernel<<<dim3(Nq/256, H, 7), 256, 0, stream>>>(
        ax, vx, pos_q, pos_k, Waq, Wvq, Wak, Wvk, Wav, Wvv, Qg, Kg, Vtg, Qe, Ke);
    attn_kernel<<<dim3(Nq/256, H, SEG), 256, 0, stream>>>(
        Qg, Kg, Vtg, Qe, Ke, partO, partL);
    finish_kernel<<<dim3(Nq/16), 256, 0, stream>>>(partO, partL, Wao, Wvo, out);
}